// Round 1
// baseline (3488.786 us; speedup 1.0000x reference)
//
#include <hip/hip_runtime.h>
#include <hip/hip_bf16.h>
#include <cstddef>

// ---------------------------------------------------------------------------
// SAGE 2-layer: scatter-mean + dual GEMM (+bias, relu) per layer. All fp32.
// Sizes (fixed by setup_inputs): N1=200000, N2=40000, N3=8000,
// E1=1280000, E2=256000, IN=128, H=256, C=47.
// ---------------------------------------------------------------------------

#define N2_DST 40000
#define N3_DST 8000
#define IN_F 128
#define H_F 256
#define C_F 47

// Edge scatter: per-edge row gather + atomic accumulate + degree count.
// FEATS must be a multiple of 4. Each thread handles one float4 of one edge.
template <int FEATS>
__global__ void scatter_sum_kernel(const float* __restrict__ hsrc,
                                   const int* __restrict__ src,
                                   const int* __restrict__ dst,
                                   float* __restrict__ s,
                                   float* __restrict__ deg,
                                   int E) {
    constexpr int F4 = FEATS / 4;
    long long idx = (long long)blockIdx.x * blockDim.x + threadIdx.x;
    int e = (int)(idx / F4);
    int f4 = (int)(idx % F4);
    if (e >= E) return;
    int sn = src[e];
    int dn = dst[e];
    const float4 v = reinterpret_cast<const float4*>(hsrc + (size_t)sn * FEATS)[f4];
    float* out = s + (size_t)dn * FEATS + (size_t)f4 * 4;
    atomicAdd(out + 0, v.x);
    atomicAdd(out + 1, v.y);
    atomicAdd(out + 2, v.z);
    atomicAdd(out + 3, v.w);
    if (f4 == 0) atomicAdd(&deg[dn], 1.0f);
}

// C[m][n] = (relu?)( sum_k Aself[m][k]*Ws[k][n] + (Asum[m][k]/max(deg[m],1))*Wn[k][n] + b[n] )
__global__ void sage_gemm_kernel(const float* __restrict__ Aself,
                                 const float* __restrict__ Asum,
                                 const float* __restrict__ deg,
                                 const float* __restrict__ Ws,
                                 const float* __restrict__ Wn,
                                 const float* __restrict__ bias,
                                 float* __restrict__ C,
                                 int M, int N, int K, int doRelu) {
    __shared__ float As[16][17];
    __shared__ float An[16][17];
    __shared__ float Bs[16][17];
    __shared__ float Bn[16][17];
    int tx = threadIdx.x, ty = threadIdx.y;
    int row = blockIdx.y * 16 + ty;
    int col = blockIdx.x * 16 + tx;
    float invd = 1.0f;
    if (row < M) invd = 1.0f / fmaxf(deg[row], 1.0f);
    float acc = 0.0f;
    for (int kt = 0; kt < K; kt += 16) {
        int ka = kt + tx;
        float a = 0.0f, an = 0.0f;
        if (row < M && ka < K) {
            a = Aself[(size_t)row * K + ka];
            an = Asum[(size_t)row * K + ka] * invd;
        }
        As[ty][tx] = a;
        An[ty][tx] = an;
        int kb = kt + ty;
        float bws = 0.0f, bwn = 0.0f;
        if (kb < K && col < N) {
            bws = Ws[(size_t)kb * N + col];
            bwn = Wn[(size_t)kb * N + col];
        }
        Bs[ty][tx] = bws;
        Bn[ty][tx] = bwn;
        __syncthreads();
#pragma unroll
        for (int k = 0; k < 16; ++k) {
            acc += As[ty][k] * Bs[k][tx];
            acc += An[ty][k] * Bn[k][tx];
        }
        __syncthreads();
    }
    if (row < M && col < N) {
        acc += bias[col];
        if (doRelu) acc = fmaxf(acc, 0.0f);
        C[(size_t)row * N + col] = acc;
    }
}

extern "C" void kernel_launch(void* const* d_in, const int* in_sizes, int n_in,
                              void* d_out, int out_size, void* d_ws, size_t ws_size,
                              hipStream_t stream) {
    const float* x       = (const float*)d_in[0];
    const int*   src1    = (const int*)d_in[1];
    const int*   dst1    = (const int*)d_in[2];
    const int*   src2    = (const int*)d_in[3];
    const int*   dst2    = (const int*)d_in[4];
    // d_in[5], d_in[6]: n_dst scalars (known statically)
    const float* W_self1 = (const float*)d_in[7];
    const float* W_neigh1= (const float*)d_in[8];
    const float* b1      = (const float*)d_in[9];
    const float* W_self2 = (const float*)d_in[10];
    const float* W_neigh2= (const float*)d_in[11];
    const float* b2      = (const float*)d_in[12];
    float* out = (float*)d_out;

    const int E1 = in_sizes[1];
    const int E2 = in_sizes[3];

    // Workspace layout (floats):
    float* ws = (float*)d_ws;
    float* s1   = ws;                                   // N2 * IN   = 5,120,000
    float* deg1 = s1 + (size_t)N2_DST * IN_F;           // N2        =    40,000
    float* h    = deg1 + N2_DST;                        // N2 * H    = 10,240,000
    float* s2   = h + (size_t)N2_DST * H_F;             // N3 * H    = 2,048,000
    float* deg2 = s2 + (size_t)N3_DST * H_F;            // N3        =     8,000

    // Zero the accumulators (harness poisons ws once; we must re-zero per call).
    hipMemsetAsync(s1, 0, (size_t)N2_DST * IN_F * sizeof(float), stream);
    hipMemsetAsync(deg1, 0, (size_t)N2_DST * sizeof(float), stream);
    hipMemsetAsync(s2, 0, (size_t)N3_DST * H_F * sizeof(float), stream);
    hipMemsetAsync(deg2, 0, (size_t)N3_DST * sizeof(float), stream);

    // Layer 1 scatter: E1 edges x 128 feats
    {
        long long threads = (long long)E1 * (IN_F / 4);
        int block = 256;
        long long grid = (threads + block - 1) / block;
        scatter_sum_kernel<IN_F><<<(dim3)(unsigned)grid, block, 0, stream>>>(
            x, src1, dst1, s1, deg1, E1);
    }

    // Layer 1 GEMM: h = relu(x[:N2] @ Wself1 + (s1/deg1) @ Wneigh1 + b1)
    {
        dim3 block(16, 16);
        dim3 grid((H_F + 15) / 16, (N2_DST + 15) / 16);
        sage_gemm_kernel<<<grid, block, 0, stream>>>(
            x, s1, deg1, W_self1, W_neigh1, b1, h, N2_DST, H_F, IN_F, 1);
    }

    // Layer 2 scatter: E2 edges x 256 feats
    {
        long long threads = (long long)E2 * (H_F / 4);
        int block = 256;
        long long grid = (threads + block - 1) / block;
        scatter_sum_kernel<H_F><<<(dim3)(unsigned)grid, block, 0, stream>>>(
            h, src2, dst2, s2, deg2, E2);
    }

    // Layer 2 GEMM: out = h[:N3] @ Wself2 + (s2/deg2) @ Wneigh2 + b2
    {
        dim3 block(16, 16);
        dim3 grid((C_F + 15) / 16, (N3_DST + 15) / 16);
        sage_gemm_kernel<<<grid, block, 0, stream>>>(
            h, s2, deg2, W_self2, W_neigh2, b2, out, N3_DST, C_F, H_F, 0);
    }
}

// Round 2
// 760.435 us; speedup vs baseline: 4.5879x; 4.5879x over previous
//
#include <hip/hip_runtime.h>
#include <hip/hip_bf16.h>
#include <cstddef>

// ---------------------------------------------------------------------------
// SAGE 2-layer. Aggregation as CSR-build + gather (no float atomics).
// Sizes fixed by setup_inputs: N1=200000, N2=40000, N3=8000,
// E1=1280000, E2=256000, IN=128, H=256, C=47.
// ---------------------------------------------------------------------------

#define N2_DST 40000
#define N3_DST 8000
#define IN_F 128
#define H_F 256
#define C_F 47

// --- CSR build ---------------------------------------------------------------

__global__ void hist_kernel(const int* __restrict__ dst, int* __restrict__ counts, int E) {
    int e = blockIdx.x * blockDim.x + threadIdx.x;
    if (e < E) atomicAdd(&counts[dst[e]], 1);
}

// Single-block exclusive scan (n up to ~64K). offsets[n] = total.
__global__ void exclusive_scan_kernel(const int* __restrict__ counts,
                                      int* __restrict__ offsets, int n) {
    __shared__ int smem[1024];
    __shared__ int carry_s;
    if (threadIdx.x == 0) carry_s = 0;
    __syncthreads();
    for (int base = 0; base < n; base += 1024) {
        int i = base + threadIdx.x;
        int v = (i < n) ? counts[i] : 0;
        smem[threadIdx.x] = v;
        __syncthreads();
        for (int off = 1; off < 1024; off <<= 1) {
            int t = (threadIdx.x >= off) ? smem[threadIdx.x - off] : 0;
            __syncthreads();
            smem[threadIdx.x] += t;
            __syncthreads();
        }
        int excl = smem[threadIdx.x] - v;
        if (i < n) offsets[i] = carry_s + excl;
        int total = smem[1023];
        __syncthreads();
        if (threadIdx.x == 0) carry_s += total;
        __syncthreads();
    }
    if (threadIdx.x == 0) offsets[n] = carry_s;
}

// Bucket-fill: edge_src_sorted[offsets[d] + rank] = src[e]
__global__ void fill_kernel(const int* __restrict__ src, const int* __restrict__ dst,
                            const int* __restrict__ offsets, int* __restrict__ cursor,
                            int* __restrict__ edge_src, int E) {
    int e = blockIdx.x * blockDim.x + threadIdx.x;
    if (e >= E) return;
    int d = dst[e];
    int pos = offsets[d] + atomicAdd(&cursor[d], 1);
    edge_src[pos] = src[e];
}

// --- Gather mean: one block per dst node, one thread per feature ------------

template <int FEATS>
__global__ void gather_mean_kernel(const float* __restrict__ hsrc,
                                   const int* __restrict__ edge_src,
                                   const int* __restrict__ offsets,
                                   float* __restrict__ hneigh) {
    int d = blockIdx.x;
    int f = threadIdx.x;  // FEATS threads per block
    int beg = offsets[d], end = offsets[d + 1];
    float s = 0.0f;
    int i = beg;
    // 2-edge unroll for a little ILP
    for (; i + 1 < end; i += 2) {
        int s0 = edge_src[i];
        int s1 = edge_src[i + 1];
        float a = hsrc[(size_t)s0 * FEATS + f];
        float b = hsrc[(size_t)s1 * FEATS + f];
        s += a;
        s += b;
    }
    if (i < end) s += hsrc[(size_t)edge_src[i] * FEATS + f];
    float deg = (float)(end - beg);
    hneigh[(size_t)d * FEATS + f] = s / fmaxf(deg, 1.0f);
}

// --- Dual GEMM: C = (relu?)(Aself@Ws + Aneigh@Wn + b) -----------------------

__global__ void sage_gemm_kernel(const float* __restrict__ Aself,
                                 const float* __restrict__ Aneigh,
                                 const float* __restrict__ Ws,
                                 const float* __restrict__ Wn,
                                 const float* __restrict__ bias,
                                 float* __restrict__ C,
                                 int M, int N, int K, int doRelu) {
    __shared__ float As[16][17];
    __shared__ float An[16][17];
    __shared__ float Bs[16][17];
    __shared__ float Bn[16][17];
    int tx = threadIdx.x, ty = threadIdx.y;
    int row = blockIdx.y * 16 + ty;
    int col = blockIdx.x * 16 + tx;
    float acc = 0.0f;
    for (int kt = 0; kt < K; kt += 16) {
        int ka = kt + tx;
        float a = 0.0f, an = 0.0f;
        if (row < M && ka < K) {
            a = Aself[(size_t)row * K + ka];
            an = Aneigh[(size_t)row * K + ka];
        }
        As[ty][tx] = a;
        An[ty][tx] = an;
        int kb = kt + ty;
        float bws = 0.0f, bwn = 0.0f;
        if (kb < K && col < N) {
            bws = Ws[(size_t)kb * N + col];
            bwn = Wn[(size_t)kb * N + col];
        }
        Bs[ty][tx] = bws;
        Bn[ty][tx] = bwn;
        __syncthreads();
#pragma unroll
        for (int k = 0; k < 16; ++k) {
            acc += As[ty][k] * Bs[k][tx];
            acc += An[ty][k] * Bn[k][tx];
        }
        __syncthreads();
    }
    if (row < M && col < N) {
        acc += bias[col];
        if (doRelu) acc = fmaxf(acc, 0.0f);
        C[(size_t)row * N + col] = acc;
    }
}

extern "C" void kernel_launch(void* const* d_in, const int* in_sizes, int n_in,
                              void* d_out, int out_size, void* d_ws, size_t ws_size,
                              hipStream_t stream) {
    const float* x        = (const float*)d_in[0];
    const int*   src1     = (const int*)d_in[1];
    const int*   dst1     = (const int*)d_in[2];
    const int*   src2     = (const int*)d_in[3];
    const int*   dst2     = (const int*)d_in[4];
    const float* W_self1  = (const float*)d_in[7];
    const float* W_neigh1 = (const float*)d_in[8];
    const float* b1       = (const float*)d_in[9];
    const float* W_self2  = (const float*)d_in[10];
    const float* W_neigh2 = (const float*)d_in[11];
    const float* b2       = (const float*)d_in[12];
    float* out = (float*)d_out;

    const int E1 = in_sizes[1];
    const int E2 = in_sizes[3];

    // Workspace layout (aliased across phases):
    //   h        : N2*H floats          (persistent, L1 output)
    //   hneigh   : max(N2*IN, N3*H)     (layer-local mean)
    //   edges    : max(E1, E2) ints     (src sorted by dst)
    //   counts, offsets, cursor : N2-sized int arrays (reused for layer 2)
    char* p = (char*)d_ws;
    float* h       = (float*)p;             p += (size_t)N2_DST * H_F * sizeof(float);
    float* hneigh  = (float*)p;             p += (size_t)N2_DST * IN_F * sizeof(float);
    int*   edges   = (int*)p;               p += (size_t)E1 * sizeof(int);
    int*   counts  = (int*)p;               p += (size_t)N2_DST * sizeof(int);
    int*   offsets = (int*)p;               p += (size_t)(N2_DST + 1) * sizeof(int);
    int*   cursor  = (int*)p;               p += (size_t)N2_DST * sizeof(int);

    // ---------------- Layer 1 ----------------
    hipMemsetAsync(counts, 0, (size_t)N2_DST * sizeof(int), stream);
    hipMemsetAsync(cursor, 0, (size_t)N2_DST * sizeof(int), stream);
    hist_kernel<<<(E1 + 255) / 256, 256, 0, stream>>>(dst1, counts, E1);
    exclusive_scan_kernel<<<1, 1024, 0, stream>>>(counts, offsets, N2_DST);
    fill_kernel<<<(E1 + 255) / 256, 256, 0, stream>>>(src1, dst1, offsets, cursor, edges, E1);
    gather_mean_kernel<IN_F><<<N2_DST, IN_F, 0, stream>>>(x, edges, offsets, hneigh);
    {
        dim3 block(16, 16);
        dim3 grid((H_F + 15) / 16, (N2_DST + 15) / 16);
        sage_gemm_kernel<<<grid, block, 0, stream>>>(
            x, hneigh, W_self1, W_neigh1, b1, h, N2_DST, H_F, IN_F, 1);
    }

    // ---------------- Layer 2 ----------------
    hipMemsetAsync(counts, 0, (size_t)N3_DST * sizeof(int), stream);
    hipMemsetAsync(cursor, 0, (size_t)N3_DST * sizeof(int), stream);
    hist_kernel<<<(E2 + 255) / 256, 256, 0, stream>>>(dst2, counts, E2);
    exclusive_scan_kernel<<<1, 1024, 0, stream>>>(counts, offsets, N3_DST);
    fill_kernel<<<(E2 + 255) / 256, 256, 0, stream>>>(src2, dst2, offsets, cursor, edges, E2);
    gather_mean_kernel<H_F><<<N3_DST, H_F, 0, stream>>>(h, edges, offsets, hneigh);
    {
        dim3 block(16, 16);
        dim3 grid((C_F + 15) / 16, (N3_DST + 15) / 16);
        sage_gemm_kernel<<<grid, block, 0, stream>>>(
            h, hneigh, W_self2, W_neigh2, b2, out, N3_DST, C_F, H_F, 0);
    }
}

// Round 3
// 460.487 us; speedup vs baseline: 7.5763x; 1.6514x over previous
//
#include <hip/hip_runtime.h>
#include <hip/hip_bf16.h>
#include <cstddef>

// ---------------------------------------------------------------------------
// SAGE 2-layer. CSR-build (hist + 3-phase scan + fill) + 4-way gather +
// register-tiled fp32 dual GEMM.
// Sizes fixed by setup_inputs: N1=200000, N2=40000, N3=8000,
// E1=1280000, E2=256000, IN=128, H=256, C=47.
// ---------------------------------------------------------------------------

#define N2_DST 40000
#define N3_DST 8000
#define IN_F 128
#define H_F 256
#define C_F 47

// --- CSR build ---------------------------------------------------------------

__global__ void hist_kernel(const int* __restrict__ dst, int* __restrict__ counts, int E) {
    int e = blockIdx.x * blockDim.x + threadIdx.x;
    if (e < E) atomicAdd(&counts[dst[e]], 1);
}

// 3-phase scan: phase1 = per-1024-chunk exclusive scan + chunk totals.
#define SCAN_CHUNK 1024
__global__ void scan_phase1(const int* __restrict__ counts, int* __restrict__ pre,
                            int* __restrict__ bsum, int n) {
    __shared__ int smem[256];
    int b = blockIdx.x, t = threadIdx.x;
    int base = b * SCAN_CHUNK + t * 4;
    int v0 = 0, v1 = 0, v2 = 0, v3 = 0;
    if (base + 3 < n) {
        int4 c = *(const int4*)&counts[base];
        v0 = c.x; v1 = c.y; v2 = c.z; v3 = c.w;
    } else {
        if (base + 0 < n) v0 = counts[base + 0];
        if (base + 1 < n) v1 = counts[base + 1];
        if (base + 2 < n) v2 = counts[base + 2];
        if (base + 3 < n) v3 = counts[base + 3];
    }
    int s = v0 + v1 + v2 + v3;
    smem[t] = s;
    __syncthreads();
    for (int off = 1; off < 256; off <<= 1) {
        int tv = (t >= off) ? smem[t - off] : 0;
        __syncthreads();
        smem[t] += tv;
        __syncthreads();
    }
    int excl = smem[t] - s;
    int p0 = excl, p1 = p0 + v0, p2 = p1 + v1, p3 = p2 + v2;
    if (base + 3 < n) {
        *(int4*)&pre[base] = make_int4(p0, p1, p2, p3);
    } else {
        if (base + 0 < n) pre[base + 0] = p0;
        if (base + 1 < n) pre[base + 1] = p1;
        if (base + 2 < n) pre[base + 2] = p2;
        if (base + 3 < n) pre[base + 3] = p3;
    }
    if (t == 255) bsum[b] = smem[255];
}

// phase2: exclusive scan of up to 256 chunk totals (single block), and write
// offsets[n] = E (grand total, known).
__global__ void scan_phase2(int* __restrict__ bsum, int nb, int* __restrict__ off_end, int E) {
    __shared__ int smem[256];
    int t = threadIdx.x;
    int v = (t < nb) ? bsum[t] : 0;
    smem[t] = v;
    __syncthreads();
    for (int off = 1; off < 256; off <<= 1) {
        int tv = (t >= off) ? smem[t - off] : 0;
        __syncthreads();
        smem[t] += tv;
        __syncthreads();
    }
    if (t < nb) bsum[t] = smem[t] - v;
    if (t == 0) *off_end = E;
}

// phase3: add chunk base to each chunk.
__global__ void scan_phase3(int* __restrict__ pre, const int* __restrict__ bsum, int n) {
    int b = blockIdx.x, t = threadIdx.x;
    int base = b * SCAN_CHUNK + t * 4;
    int add = bsum[b];
    if (base + 3 < n) {
        int4 c = *(int4*)&pre[base];
        c.x += add; c.y += add; c.z += add; c.w += add;
        *(int4*)&pre[base] = c;
    } else {
        if (base + 0 < n) pre[base + 0] += add;
        if (base + 1 < n) pre[base + 1] += add;
        if (base + 2 < n) pre[base + 2] += add;
    }
}

// Bucket-fill: edge_src[offsets[d] + rank] = src[e]
__global__ void fill_kernel(const int* __restrict__ src, const int* __restrict__ dst,
                            const int* __restrict__ offsets, int* __restrict__ cursor,
                            int* __restrict__ edge_src, int E) {
    int e = blockIdx.x * blockDim.x + threadIdx.x;
    if (e >= E) return;
    int d = dst[e];
    int pos = offsets[d] + atomicAdd(&cursor[d], 1);
    edge_src[pos] = src[e];
}

// --- Gather mean: 4 edge-groups per block, float4 per lane ------------------

template <int FEATS>
__global__ void gather_mean_kernel(const float* __restrict__ hsrc,
                                   const int* __restrict__ edge_src,
                                   const int* __restrict__ offsets,
                                   float* __restrict__ hneigh) {
    constexpr int F4 = FEATS / 4;     // 32 or 64
    constexpr int GROUPS = 4;
    __shared__ float4 red[GROUPS][F4];
    int d = blockIdx.x;
    int t = threadIdx.x;              // GROUPS*F4 threads
    int g = t / F4, l = t % F4;
    int beg = offsets[d], end = offsets[d + 1];
    float4 s = make_float4(0.f, 0.f, 0.f, 0.f);
    for (int i = beg + g; i < end; i += GROUPS) {
        int sn = edge_src[i];
        float4 v = ((const float4*)(hsrc + (size_t)sn * FEATS))[l];
        s.x += v.x; s.y += v.y; s.z += v.z; s.w += v.w;
    }
    red[g][l] = s;
    __syncthreads();
    if (g == 0) {
        float4 a = red[0][l], b = red[1][l], c = red[2][l], e4 = red[3][l];
        float inv = 1.0f / fmaxf((float)(end - beg), 1.0f);
        float4 o;
        o.x = (a.x + b.x + c.x + e4.x) * inv;
        o.y = (a.y + b.y + c.y + e4.y) * inv;
        o.z = (a.z + b.z + c.z + e4.z) * inv;
        o.w = (a.w + b.w + c.w + e4.w) * inv;
        ((float4*)(hneigh + (size_t)d * FEATS))[l] = o;
    }
}

// --- Register-tiled dual GEMM (exact tiles: M%64==0, N%64==0, K%16==0) ------
// C = (relu?)(Aself@Ws + Aneigh@Wn + b)

#define GBM 64
#define GBN 64
#define GBK 16

__global__ __launch_bounds__(256) void sage_gemm_tiled(
    const float* __restrict__ Aself, const float* __restrict__ Aneigh,
    const float* __restrict__ Ws, const float* __restrict__ Wn,
    const float* __restrict__ bias, float* __restrict__ C,
    int M, int N, int K, int doRelu) {
    __shared__ float As[GBK][GBM + 4];
    __shared__ float An[GBK][GBM + 4];
    __shared__ float Bs[GBK][GBN + 4];
    __shared__ float Bn[GBK][GBN + 4];
    int t = threadIdx.x;
    int tx = t % 16, ty = t / 16;
    int bm = blockIdx.y * GBM;
    int bn = blockIdx.x * GBN;
    float acc[4][4] = {};
    int la_r = t / 4;          // 0..63: A row in tile
    int la_k = (t % 4) * 4;    // 0,4,8,12
    int lb_k = t / 16;         // 0..15
    int lb_n = (t % 16) * 4;   // 0..60
    const size_t a_base = (size_t)(bm + la_r) * K + la_k;
    for (int kt = 0; kt < K; kt += GBK) {
        float4 a4 = *(const float4*)&Aself[a_base + kt];
        float4 n4 = *(const float4*)&Aneigh[a_base + kt];
        float4 b4 = *(const float4*)&Ws[(size_t)(kt + lb_k) * N + bn + lb_n];
        float4 w4 = *(const float4*)&Wn[(size_t)(kt + lb_k) * N + bn + lb_n];
        As[la_k + 0][la_r] = a4.x; As[la_k + 1][la_r] = a4.y;
        As[la_k + 2][la_r] = a4.z; As[la_k + 3][la_r] = a4.w;
        An[la_k + 0][la_r] = n4.x; An[la_k + 1][la_r] = n4.y;
        An[la_k + 2][la_r] = n4.z; An[la_k + 3][la_r] = n4.w;
        *(float4*)&Bs[lb_k][lb_n] = b4;
        *(float4*)&Bn[lb_k][lb_n] = w4;
        __syncthreads();
#pragma unroll
        for (int k = 0; k < GBK; ++k) {
            const float4 aS = *(const float4*)&As[k][ty * 4];
            const float4 aN = *(const float4*)&An[k][ty * 4];
            const float4 bS = *(const float4*)&Bs[k][tx * 4];
            const float4 bN = *(const float4*)&Bn[k][tx * 4];
            float av[4] = {aS.x, aS.y, aS.z, aS.w};
            float nv[4] = {aN.x, aN.y, aN.z, aN.w};
            float bv[4] = {bS.x, bS.y, bS.z, bS.w};
            float wv[4] = {bN.x, bN.y, bN.z, bN.w};
#pragma unroll
            for (int i = 0; i < 4; ++i)
#pragma unroll
                for (int j = 0; j < 4; ++j)
                    acc[i][j] += av[i] * bv[j] + nv[i] * wv[j];
        }
        __syncthreads();
    }
    int row = bm + ty * 4, col = bn + tx * 4;
    float4 bb = *(const float4*)&bias[col];
    float bbv[4] = {bb.x, bb.y, bb.z, bb.w};
#pragma unroll
    for (int i = 0; i < 4; ++i) {
        float4 o;
        o.x = acc[i][0] + bbv[0];
        o.y = acc[i][1] + bbv[1];
        o.z = acc[i][2] + bbv[2];
        o.w = acc[i][3] + bbv[3];
        if (doRelu) {
            o.x = fmaxf(o.x, 0.f); o.y = fmaxf(o.y, 0.f);
            o.z = fmaxf(o.z, 0.f); o.w = fmaxf(o.w, 0.f);
        }
        *(float4*)&C[(size_t)(row + i) * N + col] = o;
    }
}

// --- Simple guarded GEMM for ragged layer-2 (N=47) --------------------------

__global__ void sage_gemm_kernel(const float* __restrict__ Aself,
                                 const float* __restrict__ Aneigh,
                                 const float* __restrict__ Ws,
                                 const float* __restrict__ Wn,
                                 const float* __restrict__ bias,
                                 float* __restrict__ C,
                                 int M, int N, int K, int doRelu) {
    __shared__ float As[16][17];
    __shared__ float An[16][17];
    __shared__ float Bs[16][17];
    __shared__ float Bn[16][17];
    int tx = threadIdx.x, ty = threadIdx.y;
    int row = blockIdx.y * 16 + ty;
    int col = blockIdx.x * 16 + tx;
    float acc = 0.0f;
    for (int kt = 0; kt < K; kt += 16) {
        int ka = kt + tx;
        float a = 0.0f, an = 0.0f;
        if (row < M && ka < K) {
            a = Aself[(size_t)row * K + ka];
            an = Aneigh[(size_t)row * K + ka];
        }
        As[ty][tx] = a;
        An[ty][tx] = an;
        int kb = kt + ty;
        float bws = 0.0f, bwn = 0.0f;
        if (kb < K && col < N) {
            bws = Ws[(size_t)kb * N + col];
            bwn = Wn[(size_t)kb * N + col];
        }
        Bs[ty][tx] = bws;
        Bn[ty][tx] = bwn;
        __syncthreads();
#pragma unroll
        for (int k = 0; k < 16; ++k) {
            acc += As[ty][k] * Bs[k][tx];
            acc += An[ty][k] * Bn[k][tx];
        }
        __syncthreads();
    }
    if (row < M && col < N) {
        acc += bias[col];
        if (doRelu) acc = fmaxf(acc, 0.0f);
        C[(size_t)row * N + col] = acc;
    }
}

extern "C" void kernel_launch(void* const* d_in, const int* in_sizes, int n_in,
                              void* d_out, int out_size, void* d_ws, size_t ws_size,
                              hipStream_t stream) {
    const float* x        = (const float*)d_in[0];
    const int*   src1     = (const int*)d_in[1];
    const int*   dst1     = (const int*)d_in[2];
    const int*   src2     = (const int*)d_in[3];
    const int*   dst2     = (const int*)d_in[4];
    const float* W_self1  = (const float*)d_in[7];
    const float* W_neigh1 = (const float*)d_in[8];
    const float* b1       = (const float*)d_in[9];
    const float* W_self2  = (const float*)d_in[10];
    const float* W_neigh2 = (const float*)d_in[11];
    const float* b2       = (const float*)d_in[12];
    float* out = (float*)d_out;

    const int E1 = in_sizes[1];
    const int E2 = in_sizes[3];

    char* p = (char*)d_ws;
    float* h       = (float*)p;   p += (size_t)N2_DST * H_F * sizeof(float);
    float* hneigh  = (float*)p;   p += (size_t)N2_DST * IN_F * sizeof(float);
    int*   edges   = (int*)p;     p += (size_t)E1 * sizeof(int);
    int*   counts  = (int*)p;     p += (size_t)N2_DST * sizeof(int);
    int*   offsets = (int*)p;     p += (size_t)(N2_DST + 1) * sizeof(int);
    int*   cursor  = (int*)p;     p += (size_t)N2_DST * sizeof(int);
    int*   bsum    = (int*)p;     p += 256 * sizeof(int);

    // ---------------- Layer 1 ----------------
    {
        hipMemsetAsync(counts, 0, (size_t)N2_DST * sizeof(int), stream);
        hipMemsetAsync(cursor, 0, (size_t)N2_DST * sizeof(int), stream);
        hist_kernel<<<(E1 + 255) / 256, 256, 0, stream>>>(dst1, counts, E1);
        int nb = (N2_DST + SCAN_CHUNK - 1) / SCAN_CHUNK;  // 40
        scan_phase1<<<nb, 256, 0, stream>>>(counts, offsets, bsum, N2_DST);
        scan_phase2<<<1, 256, 0, stream>>>(bsum, nb, offsets + N2_DST, E1);
        scan_phase3<<<nb, 256, 0, stream>>>(offsets, bsum, N2_DST);
        fill_kernel<<<(E1 + 255) / 256, 256, 0, stream>>>(src1, dst1, offsets, cursor, edges, E1);
        gather_mean_kernel<IN_F><<<N2_DST, IN_F, 0, stream>>>(x, edges, offsets, hneigh);
        dim3 grid(H_F / GBN, N2_DST / GBM);  // 4 x 625
        sage_gemm_tiled<<<grid, 256, 0, stream>>>(
            x, hneigh, W_self1, W_neigh1, b1, h, N2_DST, H_F, IN_F, 1);
    }

    // ---------------- Layer 2 ----------------
    {
        hipMemsetAsync(counts, 0, (size_t)N3_DST * sizeof(int), stream);
        hipMemsetAsync(cursor, 0, (size_t)N3_DST * sizeof(int), stream);
        hist_kernel<<<(E2 + 255) / 256, 256, 0, stream>>>(dst2, counts, E2);
        int nb = (N3_DST + SCAN_CHUNK - 1) / SCAN_CHUNK;  // 8
        scan_phase1<<<nb, 256, 0, stream>>>(counts, offsets, bsum, N3_DST);
        scan_phase2<<<1, 256, 0, stream>>>(bsum, nb, offsets + N3_DST, E2);
        scan_phase3<<<nb, 256, 0, stream>>>(offsets, bsum, N3_DST);
        fill_kernel<<<(E2 + 255) / 256, 256, 0, stream>>>(src2, dst2, offsets, cursor, edges, E2);
        gather_mean_kernel<H_F><<<N3_DST, H_F, 0, stream>>>(h, edges, offsets, hneigh);
        dim3 block(16, 16);
        dim3 grid((C_F + 15) / 16, (N3_DST + 15) / 16);
        sage_gemm_kernel<<<grid, block, 0, stream>>>(
            h, hneigh, W_self2, W_neigh2, b2, out, N3_DST, C_F, H_F, 0);
    }
}

// Round 4
// 372.808 us; speedup vs baseline: 9.3581x; 1.2352x over previous
//
#include <hip/hip_runtime.h>
#include <hip/hip_bf16.h>
#include <cstddef>

// ---------------------------------------------------------------------------
// SAGE 2-layer, bf16/MFMA edition.
// Pipeline per layer: CSR build (hist + 3-phase scan + fill) -> bf16 gather-mean
// -> fused dual GEMM as single MFMA GEMM over concatenated K:
//      C = [A_self | A_neigh] @ [W_self ; W_neigh] + b
// Sizes fixed: N1=200000, N2=40000, N3=8000, E1=1280000, E2=256000,
// IN=128, H=256, C=47.
// ---------------------------------------------------------------------------

#define N1_SRC 200000
#define N2_DST 40000
#define N3_DST 8000
#define IN_F 128
#define H_F 256
#define C_F 47

typedef short bf16x8 __attribute__((ext_vector_type(8)));
typedef float f32x4 __attribute__((ext_vector_type(4)));

__device__ __forceinline__ float bf2f(ushort u) {
    union { uint i; float f; } v; v.i = ((uint)u) << 16; return v.f;
}
__device__ __forceinline__ ushort f2bf(float f) {
    union { float f; uint i; } v; v.f = f;
    uint r = v.i + 0x7FFF + ((v.i >> 16) & 1);
    return (ushort)(r >> 16);
}

// --- bf16 cast of x ---------------------------------------------------------

__global__ void cast_f32_to_bf16(const float* __restrict__ in,
                                 ushort* __restrict__ out, int n4) {
    int i = blockIdx.x * blockDim.x + threadIdx.x;
    if (i >= n4) return;
    float4 v = ((const float4*)in)[i];
    ushort4 o;
    o.x = f2bf(v.x); o.y = f2bf(v.y); o.z = f2bf(v.z); o.w = f2bf(v.w);
    ((ushort4*)out)[i] = o;
}

// --- weight prep: WT[n][k] = bf16( k<KS ? Wself[k][n] : Wneigh[k-KS][n] ), pad n>=N with 0

__global__ void build_wt(const float* __restrict__ Wself, const float* __restrict__ Wneigh,
                         ushort* __restrict__ WT, int N, int KS, int KN) {
    int n = blockIdx.x;
    int K = KS + KN;
    for (int k = threadIdx.x; k < K; k += blockDim.x) {
        float v = 0.f;
        if (n < N) v = (k < KS) ? Wself[(size_t)k * N + n] : Wneigh[(size_t)(k - KS) * N + n];
        WT[(size_t)n * K + k] = f2bf(v);
    }
}

__global__ void pad_bias(const float* __restrict__ b, float* __restrict__ bp, int n, int np) {
    int i = threadIdx.x;
    if (i < np) bp[i] = (i < n) ? b[i] : 0.f;
}

// --- CSR build ---------------------------------------------------------------

__global__ void hist_kernel(const int* __restrict__ dst, int* __restrict__ counts, int E) {
    int e = blockIdx.x * blockDim.x + threadIdx.x;
    if (e < E) atomicAdd(&counts[dst[e]], 1);
}

#define SCAN_CHUNK 1024
__global__ void scan_phase1(const int* __restrict__ counts, int* __restrict__ pre,
                            int* __restrict__ bsum, int n) {
    __shared__ int smem[256];
    int b = blockIdx.x, t = threadIdx.x;
    int base = b * SCAN_CHUNK + t * 4;
    int v0 = 0, v1 = 0, v2 = 0, v3 = 0;
    if (base + 3 < n) {
        int4 c = *(const int4*)&counts[base];
        v0 = c.x; v1 = c.y; v2 = c.z; v3 = c.w;
    } else {
        if (base + 0 < n) v0 = counts[base + 0];
        if (base + 1 < n) v1 = counts[base + 1];
        if (base + 2 < n) v2 = counts[base + 2];
        if (base + 3 < n) v3 = counts[base + 3];
    }
    int s = v0 + v1 + v2 + v3;
    smem[t] = s;
    __syncthreads();
    for (int off = 1; off < 256; off <<= 1) {
        int tv = (t >= off) ? smem[t - off] : 0;
        __syncthreads();
        smem[t] += tv;
        __syncthreads();
    }
    int excl = smem[t] - s;
    int p0 = excl, p1 = p0 + v0, p2 = p1 + v1, p3 = p2 + v2;
    if (base + 3 < n) {
        *(int4*)&pre[base] = make_int4(p0, p1, p2, p3);
    } else {
        if (base + 0 < n) pre[base + 0] = p0;
        if (base + 1 < n) pre[base + 1] = p1;
        if (base + 2 < n) pre[base + 2] = p2;
        if (base + 3 < n) pre[base + 3] = p3;
    }
    if (t == 255) bsum[b] = smem[255];
}

__global__ void scan_phase2(int* __restrict__ bsum, int nb, int* __restrict__ off_end, int E) {
    __shared__ int smem[256];
    int t = threadIdx.x;
    int v = (t < nb) ? bsum[t] : 0;
    smem[t] = v;
    __syncthreads();
    for (int off = 1; off < 256; off <<= 1) {
        int tv = (t >= off) ? smem[t - off] : 0;
        __syncthreads();
        smem[t] += tv;
        __syncthreads();
    }
    if (t < nb) bsum[t] = smem[t] - v;
    if (t == 0) *off_end = E;
}

__global__ void scan_phase3(int* __restrict__ pre, const int* __restrict__ bsum, int n) {
    int b = blockIdx.x, t = threadIdx.x;
    int base = b * SCAN_CHUNK + t * 4;
    int add = bsum[b];
    if (base + 3 < n) {
        int4 c = *(int4*)&pre[base];
        c.x += add; c.y += add; c.z += add; c.w += add;
        *(int4*)&pre[base] = c;
    } else {
        if (base + 0 < n) pre[base + 0] += add;
        if (base + 1 < n) pre[base + 1] += add;
        if (base + 2 < n) pre[base + 2] += add;
    }
}

__global__ void fill_kernel(const int* __restrict__ src, const int* __restrict__ dst,
                            const int* __restrict__ offsets, int* __restrict__ cursor,
                            int* __restrict__ edge_src, int E) {
    int e = blockIdx.x * blockDim.x + threadIdx.x;
    if (e >= E) return;
    int d = dst[e];
    int pos = offsets[d] + atomicAdd(&cursor[d], 1);
    edge_src[pos] = src[e];
}

// --- bf16 gather-mean: one dst per block, 4 waves deep over edges -----------
// FEATS=128: lane covers 2 feats (uint). Row = 256 B = 64 lanes x 4 B.

__global__ __launch_bounds__(256) void gather_mean_f128(
    const ushort* __restrict__ xb, const int* __restrict__ edges,
    const int* __restrict__ offsets, ushort* __restrict__ outb) {
    __shared__ float2 red[4][64];
    int d = blockIdx.x;
    int t = threadIdx.x, lane = t & 63, w = t >> 6;
    int beg = offsets[d], end = offsets[d + 1];
    float sx = 0.f, sy = 0.f;
    for (int i = beg + w; i < end; i += 4) {
        int sn = edges[i];
        uint v = ((const uint*)(xb + (size_t)sn * IN_F))[lane];
        sx += bf2f((ushort)(v & 0xffff));
        sy += bf2f((ushort)(v >> 16));
    }
    red[w][lane] = make_float2(sx, sy);
    __syncthreads();
    if (w == 0) {
        float2 a = red[0][lane], b = red[1][lane], c = red[2][lane], e = red[3][lane];
        float inv = 1.0f / fmaxf((float)(end - beg), 1.0f);
        float ox = (a.x + b.x + c.x + e.x) * inv;
        float oy = (a.y + b.y + c.y + e.y) * inv;
        ((uint*)(outb + (size_t)d * IN_F))[lane] = (uint)f2bf(ox) | ((uint)f2bf(oy) << 16);
    }
}

// FEATS=256: lane covers 4 feats (uint2 = 8 B). Row = 512 B.
__global__ __launch_bounds__(256) void gather_mean_f256(
    const ushort* __restrict__ hb, const int* __restrict__ edges,
    const int* __restrict__ offsets, ushort* __restrict__ outb) {
    __shared__ float4 red[4][64];
    int d = blockIdx.x;
    int t = threadIdx.x, lane = t & 63, w = t >> 6;
    int beg = offsets[d], end = offsets[d + 1];
    float s0 = 0.f, s1 = 0.f, s2 = 0.f, s3 = 0.f;
    for (int i = beg + w; i < end; i += 4) {
        int sn = edges[i];
        uint2 v = ((const uint2*)(hb + (size_t)sn * H_F))[lane];
        s0 += bf2f((ushort)(v.x & 0xffff));
        s1 += bf2f((ushort)(v.x >> 16));
        s2 += bf2f((ushort)(v.y & 0xffff));
        s3 += bf2f((ushort)(v.y >> 16));
    }
    red[w][lane] = make_float4(s0, s1, s2, s3);
    __syncthreads();
    if (w == 0) {
        float4 a = red[0][lane], b = red[1][lane], c = red[2][lane], e = red[3][lane];
        float inv = 1.0f / fmaxf((float)(end - beg), 1.0f);
        float o0 = (a.x + b.x + c.x + e.x) * inv;
        float o1 = (a.y + b.y + c.y + e.y) * inv;
        float o2 = (a.z + b.z + c.z + e.z) * inv;
        float o3 = (a.w + b.w + c.w + e.w) * inv;
        uint2 o;
        o.x = (uint)f2bf(o0) | ((uint)f2bf(o1) << 16);
        o.y = (uint)f2bf(o2) | ((uint)f2bf(o3) << 16);
        ((uint2*)(outb + (size_t)d * H_F))[lane] = o;
    }
}

// --- MFMA GEMM: C = (relu?)([Aself|Aneigh] @ WT^T + bias) -------------------
// Block tile 64x64, 4 waves (2x2), each wave 32x32 via 2x2 frags of 16x16x32.
// A rows bf16 (KSELF from Aself, K-KSELF from Aneigh); WT is [Ntot][K] bf16.
// M % 64 == 0. N tile exact (WT pre-padded); store guard col < ncols for f32 out.

template <int K, int KSELF, bool RELU, bool OUTF32>
__global__ __launch_bounds__(256) void sage_mfma_gemm(
    const ushort* __restrict__ Aself, const ushort* __restrict__ Aneigh,
    const ushort* __restrict__ WT, const float* __restrict__ bias,
    void* __restrict__ Cout, int ldc, int ncols) {
    constexpr int KN = K - KSELF;
    constexpr int LDL = K + 8;  // LDS row stride in elems (+16B pad: 2-way conflicts only)
    __shared__ __align__(16) ushort A_lds[64 * LDL];
    __shared__ __align__(16) ushort B_lds[64 * LDL];
    int t = threadIdx.x;
    int bn = blockIdx.x * 64, bm = blockIdx.y * 64;
    constexpr int CPR = K / 8;            // 16B chunks per row
    constexpr int ITER = 64 * CPR / 256;  // staging iterations
#pragma unroll
    for (int c = 0; c < ITER; ++c) {
        int id = c * 256 + t;
        int row = id / CPR;
        int kc = (id % CPR) * 8;
        const ushort* sa = (kc < KSELF)
                               ? Aself + (size_t)(bm + row) * KSELF + kc
                               : Aneigh + (size_t)(bm + row) * KN + (kc - KSELF);
        float4 av = *(const float4*)sa;
        float4 bv = *(const float4*)(WT + (size_t)(bn + row) * K + kc);
        *(float4*)&A_lds[row * LDL + kc] = av;
        *(float4*)&B_lds[row * LDL + kc] = bv;
    }
    __syncthreads();
    int lane = t & 63, w = t >> 6;
    int wr = w >> 1, wc = w & 1;
    int ln = lane & 15, kh = lane >> 4;
    const ushort* Ab = &A_lds[(wr * 32 + ln) * LDL + kh * 8];
    const ushort* Bb = &B_lds[(wc * 32 + ln) * LDL + kh * 8];
    f32x4 acc00 = {0.f, 0.f, 0.f, 0.f};
    f32x4 acc01 = {0.f, 0.f, 0.f, 0.f};
    f32x4 acc10 = {0.f, 0.f, 0.f, 0.f};
    f32x4 acc11 = {0.f, 0.f, 0.f, 0.f};
#pragma unroll
    for (int kt = 0; kt < K / 32; ++kt) {
        bf16x8 a0 = *(const bf16x8*)(Ab + kt * 32);
        bf16x8 a1 = *(const bf16x8*)(Ab + 16 * LDL + kt * 32);
        bf16x8 b0 = *(const bf16x8*)(Bb + kt * 32);
        bf16x8 b1 = *(const bf16x8*)(Bb + 16 * LDL + kt * 32);
        acc00 = __builtin_amdgcn_mfma_f32_16x16x32_bf16(a0, b0, acc00, 0, 0, 0);
        acc01 = __builtin_amdgcn_mfma_f32_16x16x32_bf16(a0, b1, acc01, 0, 0, 0);
        acc10 = __builtin_amdgcn_mfma_f32_16x16x32_bf16(a1, b0, acc10, 0, 0, 0);
        acc11 = __builtin_amdgcn_mfma_f32_16x16x32_bf16(a1, b1, acc11, 0, 0, 0);
    }
    // Epilogue. C/D layout: col = lane&15, row = (lane>>4)*4 + reg.
    f32x4 accs[2][2] = {{acc00, acc01}, {acc10, acc11}};
#pragma unroll
    for (int m = 0; m < 2; ++m) {
#pragma unroll
        for (int n = 0; n < 2; ++n) {
            int col = bn + wc * 32 + n * 16 + ln;
            float bv = bias[col];
#pragma unroll
            for (int r = 0; r < 4; ++r) {
                int row = bm + wr * 32 + m * 16 + kh * 4 + r;
                float v = accs[m][n][r] + bv;
                if (RELU) v = fmaxf(v, 0.f);
                if (OUTF32) {
                    if (col < ncols) ((float*)Cout)[(size_t)row * ncols + col] = v;
                } else {
                    ((ushort*)Cout)[(size_t)row * ldc + col] = f2bf(v);
                }
            }
        }
    }
}

// ---------------------------------------------------------------------------

static inline char* carve(char*& p, size_t bytes) {
    char* r = p;
    p += (bytes + 255) & ~(size_t)255;
    return r;
}

extern "C" void kernel_launch(void* const* d_in, const int* in_sizes, int n_in,
                              void* d_out, int out_size, void* d_ws, size_t ws_size,
                              hipStream_t stream) {
    const float* x        = (const float*)d_in[0];
    const int*   src1     = (const int*)d_in[1];
    const int*   dst1     = (const int*)d_in[2];
    const int*   src2     = (const int*)d_in[3];
    const int*   dst2     = (const int*)d_in[4];
    const float* W_self1  = (const float*)d_in[7];
    const float* W_neigh1 = (const float*)d_in[8];
    const float* b1       = (const float*)d_in[9];
    const float* W_self2  = (const float*)d_in[10];
    const float* W_neigh2 = (const float*)d_in[11];
    const float* b2       = (const float*)d_in[12];
    float* out = (float*)d_out;

    const int E1 = in_sizes[1];
    const int E2 = in_sizes[3];

    char* p = (char*)d_ws;
    ushort* xb       = (ushort*)carve(p, (size_t)N1_SRC * IN_F * 2);   // 51.2 MB
    ushort* hb       = (ushort*)carve(p, (size_t)N2_DST * H_F * 2);    // 20.5 MB
    ushort* hneighb  = (ushort*)carve(p, (size_t)N2_DST * IN_F * 2);   // 10.2 MB
    ushort* hneigh2b = (ushort*)carve(p, (size_t)N3_DST * H_F * 2);    //  4.1 MB
    int*    edges    = (int*)carve(p, (size_t)E1 * 4);                 //  5.1 MB
    int*    counts   = (int*)carve(p, (size_t)N2_DST * 4);
    int*    offsets  = (int*)carve(p, (size_t)(N2_DST + 1) * 4);
    int*    cursor   = (int*)carve(p, (size_t)N2_DST * 4);
    int*    bsum     = (int*)carve(p, 256 * 4);
    ushort* WT1      = (ushort*)carve(p, (size_t)H_F * (IN_F * 2) * 2);  // 256x256 bf16
    ushort* WT2      = (ushort*)carve(p, (size_t)64 * (H_F * 2) * 2);    // 64x512 bf16
    float*  bias2p   = (float*)carve(p, 64 * 4);

    // --- one-time-per-call prep (cheap) ---
    {
        int n4 = N1_SRC * IN_F / 4;
        cast_f32_to_bf16<<<(n4 + 255) / 256, 256, 0, stream>>>(x, xb, n4);
        build_wt<<<H_F, 256, 0, stream>>>(W_self1, W_neigh1, WT1, H_F, IN_F, IN_F);
        build_wt<<<64, 256, 0, stream>>>(W_self2, W_neigh2, WT2, C_F, H_F, H_F);
        pad_bias<<<1, 64, 0, stream>>>(b2, bias2p, C_F, 64);
    }

    // ---------------- Layer 1 ----------------
    {
        hipMemsetAsync(counts, 0, (size_t)N2_DST * 4, stream);
        hipMemsetAsync(cursor, 0, (size_t)N2_DST * 4, stream);
        hist_kernel<<<(E1 + 255) / 256, 256, 0, stream>>>(dst1, counts, E1);
        int nb = (N2_DST + SCAN_CHUNK - 1) / SCAN_CHUNK;  // 40
        scan_phase1<<<nb, 256, 0, stream>>>(counts, offsets, bsum, N2_DST);
        scan_phase2<<<1, 256, 0, stream>>>(bsum, nb, offsets + N2_DST, E1);
        scan_phase3<<<nb, 256, 0, stream>>>(offsets, bsum, N2_DST);
        fill_kernel<<<(E1 + 255) / 256, 256, 0, stream>>>(src1, dst1, offsets, cursor, edges, E1);
        gather_mean_f128<<<N2_DST, 256, 0, stream>>>(xb, edges, offsets, hneighb);
        dim3 grid(H_F / 64, N2_DST / 64);  // 4 x 625
        sage_mfma_gemm<256, 128, true, false><<<grid, 256, 0, stream>>>(
            xb, hneighb, WT1, b1, hb, H_F, H_F);
    }

    // ---------------- Layer 2 ----------------
    {
        hipMemsetAsync(counts, 0, (size_t)N3_DST * 4, stream);
        hipMemsetAsync(cursor, 0, (size_t)N3_DST * 4, stream);
        hist_kernel<<<(E2 + 255) / 256, 256, 0, stream>>>(dst2, counts, E2);
        int nb = (N3_DST + SCAN_CHUNK - 1) / SCAN_CHUNK;  // 8
        scan_phase1<<<nb, 256, 0, stream>>>(counts, offsets, bsum, N3_DST);
        scan_phase2<<<1, 256, 0, stream>>>(bsum, nb, offsets + N3_DST, E2);
        scan_phase3<<<nb, 256, 0, stream>>>(offsets, bsum, N3_DST);
        fill_kernel<<<(E2 + 255) / 256, 256, 0, stream>>>(src2, dst2, offsets, cursor, edges, E2);
        gather_mean_f256<<<N3_DST, 256, 0, stream>>>(hb, edges, offsets, hneigh2b);
        dim3 grid(1, N3_DST / 64);  // 1 x 125
        sage_mfma_gemm<512, 256, false, true><<<grid, 256, 0, stream>>>(
            hb, hneigh2b, WT2, bias2p, out, C_F, C_F);
    }
}

// Round 5
// 298.519 us; speedup vs baseline: 11.6870x; 1.2489x over previous
//
#include <hip/hip_runtime.h>
#include <hip/hip_bf16.h>
#include <cstddef>

// ---------------------------------------------------------------------------
// SAGE 2-layer, bf16/MFMA edition, wave-per-dst ILP gathers.
// Pipeline per layer: CSR build (hist + 3-phase scan + fill) -> bf16 gather-mean
// -> fused dual GEMM as single MFMA GEMM over concatenated K:
//      C = [A_self | A_neigh] @ [W_self ; W_neigh] + b
// Sizes fixed: N1=200000, N2=40000, N3=8000, E1=1280000, E2=256000,
// IN=128, H=256, C=47.
// ---------------------------------------------------------------------------

#define N1_SRC 200000
#define N2_DST 40000
#define N3_DST 8000
#define IN_F 128
#define H_F 256
#define C_F 47

typedef short bf16x8 __attribute__((ext_vector_type(8)));
typedef float f32x4 __attribute__((ext_vector_type(4)));

__device__ __forceinline__ float bf2f(ushort u) {
    union { uint i; float f; } v; v.i = ((uint)u) << 16; return v.f;
}
__device__ __forceinline__ ushort f2bf(float f) {
    union { float f; uint i; } v; v.f = f;
    uint r = v.i + 0x7FFF + ((v.i >> 16) & 1);
    return (ushort)(r >> 16);
}

// --- bf16 cast of x ---------------------------------------------------------

__global__ void cast_f32_to_bf16(const float* __restrict__ in,
                                 ushort* __restrict__ out, int n4) {
    int i = blockIdx.x * blockDim.x + threadIdx.x;
    if (i >= n4) return;
    float4 v = ((const float4*)in)[i];
    ushort4 o;
    o.x = f2bf(v.x); o.y = f2bf(v.y); o.z = f2bf(v.z); o.w = f2bf(v.w);
    ((ushort4*)out)[i] = o;
}

// --- weight prep: WT[n][k] = bf16( k<KS ? Wself[k][n] : Wneigh[k-KS][n] ), pad n>=N with 0

__global__ void build_wt(const float* __restrict__ Wself, const float* __restrict__ Wneigh,
                         ushort* __restrict__ WT, int N, int KS, int KN) {
    int n = blockIdx.x;
    int K = KS + KN;
    for (int k = threadIdx.x; k < K; k += blockDim.x) {
        float v = 0.f;
        if (n < N) v = (k < KS) ? Wself[(size_t)k * N + n] : Wneigh[(size_t)(k - KS) * N + n];
        WT[(size_t)n * K + k] = f2bf(v);
    }
}

__global__ void pad_bias(const float* __restrict__ b, float* __restrict__ bp, int n, int np) {
    int i = threadIdx.x;
    if (i < np) bp[i] = (i < n) ? b[i] : 0.f;
}

// --- CSR build ---------------------------------------------------------------

__global__ void hist_kernel(const int* __restrict__ dst, int* __restrict__ counts, int E) {
    int e = blockIdx.x * blockDim.x + threadIdx.x;
    if (e < E) atomicAdd(&counts[dst[e]], 1);
}

#define SCAN_CHUNK 1024
__global__ void scan_phase1(const int* __restrict__ counts, int* __restrict__ pre,
                            int* __restrict__ bsum, int n) {
    __shared__ int smem[256];
    int b = blockIdx.x, t = threadIdx.x;
    int base = b * SCAN_CHUNK + t * 4;
    int v0 = 0, v1 = 0, v2 = 0, v3 = 0;
    if (base + 3 < n) {
        int4 c = *(const int4*)&counts[base];
        v0 = c.x; v1 = c.y; v2 = c.z; v3 = c.w;
    } else {
        if (base + 0 < n) v0 = counts[base + 0];
        if (base + 1 < n) v1 = counts[base + 1];
        if (base + 2 < n) v2 = counts[base + 2];
        if (base + 3 < n) v3 = counts[base + 3];
    }
    int s = v0 + v1 + v2 + v3;
    smem[t] = s;
    __syncthreads();
    for (int off = 1; off < 256; off <<= 1) {
        int tv = (t >= off) ? smem[t - off] : 0;
        __syncthreads();
        smem[t] += tv;
        __syncthreads();
    }
    int excl = smem[t] - s;
    int p0 = excl, p1 = p0 + v0, p2 = p1 + v1, p3 = p2 + v2;
    if (base + 3 < n) {
        *(int4*)&pre[base] = make_int4(p0, p1, p2, p3);
    } else {
        if (base + 0 < n) pre[base + 0] = p0;
        if (base + 1 < n) pre[base + 1] = p1;
        if (base + 2 < n) pre[base + 2] = p2;
        if (base + 3 < n) pre[base + 3] = p3;
    }
    if (t == 255) bsum[b] = smem[255];
}

__global__ void scan_phase2(int* __restrict__ bsum, int nb, int* __restrict__ off_end, int E) {
    __shared__ int smem[256];
    int t = threadIdx.x;
    int v = (t < nb) ? bsum[t] : 0;
    smem[t] = v;
    __syncthreads();
    for (int off = 1; off < 256; off <<= 1) {
        int tv = (t >= off) ? smem[t - off] : 0;
        __syncthreads();
        smem[t] += tv;
        __syncthreads();
    }
    if (t < nb) bsum[t] = smem[t] - v;
    if (t == 0) *off_end = E;
}

__global__ void scan_phase3(int* __restrict__ pre, const int* __restrict__ bsum, int n) {
    int b = blockIdx.x, t = threadIdx.x;
    int base = b * SCAN_CHUNK + t * 4;
    int add = bsum[b];
    if (base + 3 < n) {
        int4 c = *(int4*)&pre[base];
        c.x += add; c.y += add; c.z += add; c.w += add;
        *(int4*)&pre[base] = c;
    } else {
        if (base + 0 < n) pre[base + 0] += add;
        if (base + 1 < n) pre[base + 1] += add;
        if (base + 2 < n) pre[base + 2] += add;
    }
}

__global__ void fill_kernel(const int* __restrict__ src, const int* __restrict__ dst,
                            const int* __restrict__ offsets, int* __restrict__ cursor,
                            int* __restrict__ edge_src, int E) {
    int e = blockIdx.x * blockDim.x + threadIdx.x;
    if (e >= E) return;
    int d = dst[e];
    int pos = offsets[d] + atomicAdd(&cursor[d], 1);
    edge_src[pos] = src[e];
}

// --- Wave-per-dst bf16 gather-mean, deep ILP, no LDS / no barriers ----------
// f128: 64 lanes x 4 B (uint = 2 bf16) = one 256 B row; lane owns its 2 feats.

__global__ __launch_bounds__(256) void gather_mean_f128(
    const ushort* __restrict__ xb, const int* __restrict__ edges,
    const int* __restrict__ offsets, ushort* __restrict__ outb) {
    int d = (blockIdx.x << 2) | (threadIdx.x >> 6);   // wave-per-dst, 4 waves/block
    int lane = threadIdx.x & 63;
    int beg = offsets[d], end = offsets[d + 1];
    float sx = 0.f, sy = 0.f;
    int i = beg;
    // 8-deep: 8 independent row loads in flight
    for (; i + 7 < end; i += 8) {
        int e0 = edges[i + 0], e1 = edges[i + 1], e2 = edges[i + 2], e3 = edges[i + 3];
        int e4 = edges[i + 4], e5 = edges[i + 5], e6 = edges[i + 6], e7 = edges[i + 7];
        uint v0 = ((const uint*)(xb + (size_t)e0 * IN_F))[lane];
        uint v1 = ((const uint*)(xb + (size_t)e1 * IN_F))[lane];
        uint v2 = ((const uint*)(xb + (size_t)e2 * IN_F))[lane];
        uint v3 = ((const uint*)(xb + (size_t)e3 * IN_F))[lane];
        uint v4 = ((const uint*)(xb + (size_t)e4 * IN_F))[lane];
        uint v5 = ((const uint*)(xb + (size_t)e5 * IN_F))[lane];
        uint v6 = ((const uint*)(xb + (size_t)e6 * IN_F))[lane];
        uint v7 = ((const uint*)(xb + (size_t)e7 * IN_F))[lane];
        sx += bf2f((ushort)(v0 & 0xffff)); sy += bf2f((ushort)(v0 >> 16));
        sx += bf2f((ushort)(v1 & 0xffff)); sy += bf2f((ushort)(v1 >> 16));
        sx += bf2f((ushort)(v2 & 0xffff)); sy += bf2f((ushort)(v2 >> 16));
        sx += bf2f((ushort)(v3 & 0xffff)); sy += bf2f((ushort)(v3 >> 16));
        sx += bf2f((ushort)(v4 & 0xffff)); sy += bf2f((ushort)(v4 >> 16));
        sx += bf2f((ushort)(v5 & 0xffff)); sy += bf2f((ushort)(v5 >> 16));
        sx += bf2f((ushort)(v6 & 0xffff)); sy += bf2f((ushort)(v6 >> 16));
        sx += bf2f((ushort)(v7 & 0xffff)); sy += bf2f((ushort)(v7 >> 16));
    }
    for (; i < end; ++i) {
        uint v = ((const uint*)(xb + (size_t)edges[i] * IN_F))[lane];
        sx += bf2f((ushort)(v & 0xffff));
        sy += bf2f((ushort)(v >> 16));
    }
    float inv = 1.0f / fmaxf((float)(end - beg), 1.0f);
    ((uint*)(outb + (size_t)d * IN_F))[lane] =
        (uint)f2bf(sx * inv) | ((uint)f2bf(sy * inv) << 16);
}

// f256: 64 lanes x 8 B (uint2 = 4 bf16) = one 512 B row; lane owns 4 feats.
__global__ __launch_bounds__(256) void gather_mean_f256(
    const ushort* __restrict__ hb, const int* __restrict__ edges,
    const int* __restrict__ offsets, ushort* __restrict__ outb) {
    int d = (blockIdx.x << 2) | (threadIdx.x >> 6);
    int lane = threadIdx.x & 63;
    int beg = offsets[d], end = offsets[d + 1];
    float s0 = 0.f, s1 = 0.f, s2 = 0.f, s3 = 0.f;
    int i = beg;
    for (; i + 3 < end; i += 4) {
        int e0 = edges[i + 0], e1 = edges[i + 1], e2 = edges[i + 2], e3 = edges[i + 3];
        uint2 v0 = ((const uint2*)(hb + (size_t)e0 * H_F))[lane];
        uint2 v1 = ((const uint2*)(hb + (size_t)e1 * H_F))[lane];
        uint2 v2 = ((const uint2*)(hb + (size_t)e2 * H_F))[lane];
        uint2 v3 = ((const uint2*)(hb + (size_t)e3 * H_F))[lane];
        s0 += bf2f((ushort)(v0.x & 0xffff)); s1 += bf2f((ushort)(v0.x >> 16));
        s2 += bf2f((ushort)(v0.y & 0xffff)); s3 += bf2f((ushort)(v0.y >> 16));
        s0 += bf2f((ushort)(v1.x & 0xffff)); s1 += bf2f((ushort)(v1.x >> 16));
        s2 += bf2f((ushort)(v1.y & 0xffff)); s3 += bf2f((ushort)(v1.y >> 16));
        s0 += bf2f((ushort)(v2.x & 0xffff)); s1 += bf2f((ushort)(v2.x >> 16));
        s2 += bf2f((ushort)(v2.y & 0xffff)); s3 += bf2f((ushort)(v2.y >> 16));
        s0 += bf2f((ushort)(v3.x & 0xffff)); s1 += bf2f((ushort)(v3.x >> 16));
        s2 += bf2f((ushort)(v3.y & 0xffff)); s3 += bf2f((ushort)(v3.y >> 16));
    }
    for (; i < end; ++i) {
        uint2 v = ((const uint2*)(hb + (size_t)edges[i] * H_F))[lane];
        s0 += bf2f((ushort)(v.x & 0xffff)); s1 += bf2f((ushort)(v.x >> 16));
        s2 += bf2f((ushort)(v.y & 0xffff)); s3 += bf2f((ushort)(v.y >> 16));
    }
    float inv = 1.0f / fmaxf((float)(end - beg), 1.0f);
    uint2 o;
    o.x = (uint)f2bf(s0 * inv) | ((uint)f2bf(s1 * inv) << 16);
    o.y = (uint)f2bf(s2 * inv) | ((uint)f2bf(s3 * inv) << 16);
    ((uint2*)(outb + (size_t)d * H_F))[lane] = o;
}

// --- MFMA GEMM: C = (relu?)([Aself|Aneigh] @ WT^T + bias) -------------------
// Block tile 64x64, 4 waves (2x2), each wave 32x32 via 2x2 frags of 16x16x32.

template <int K, int KSELF, bool RELU, bool OUTF32>
__global__ __launch_bounds__(256) void sage_mfma_gemm(
    const ushort* __restrict__ Aself, const ushort* __restrict__ Aneigh,
    const ushort* __restrict__ WT, const float* __restrict__ bias,
    void* __restrict__ Cout, int ldc, int ncols) {
    constexpr int KN = K - KSELF;
    constexpr int LDL = K + 8;  // LDS row stride in elems (+16B pad: 2-way conflicts only)
    __shared__ __align__(16) ushort A_lds[64 * LDL];
    __shared__ __align__(16) ushort B_lds[64 * LDL];
    int t = threadIdx.x;
    int bn = blockIdx.x * 64, bm = blockIdx.y * 64;
    constexpr int CPR = K / 8;            // 16B chunks per row
    constexpr int ITER = 64 * CPR / 256;  // staging iterations
#pragma unroll
    for (int c = 0; c < ITER; ++c) {
        int id = c * 256 + t;
        int row = id / CPR;
        int kc = (id % CPR) * 8;
        const ushort* sa = (kc < KSELF)
                               ? Aself + (size_t)(bm + row) * KSELF + kc
                               : Aneigh + (size_t)(bm + row) * KN + (kc - KSELF);
        float4 av = *(const float4*)sa;
        float4 bv = *(const float4*)(WT + (size_t)(bn + row) * K + kc);
        *(float4*)&A_lds[row * LDL + kc] = av;
        *(float4*)&B_lds[row * LDL + kc] = bv;
    }
    __syncthreads();
    int lane = t & 63, w = t >> 6;
    int wr = w >> 1, wc = w & 1;
    int ln = lane & 15, kh = lane >> 4;
    const ushort* Ab = &A_lds[(wr * 32 + ln) * LDL + kh * 8];
    const ushort* Bb = &B_lds[(wc * 32 + ln) * LDL + kh * 8];
    f32x4 acc00 = {0.f, 0.f, 0.f, 0.f};
    f32x4 acc01 = {0.f, 0.f, 0.f, 0.f};
    f32x4 acc10 = {0.f, 0.f, 0.f, 0.f};
    f32x4 acc11 = {0.f, 0.f, 0.f, 0.f};
#pragma unroll
    for (int kt = 0; kt < K / 32; ++kt) {
        bf16x8 a0 = *(const bf16x8*)(Ab + kt * 32);
        bf16x8 a1 = *(const bf16x8*)(Ab + 16 * LDL + kt * 32);
        bf16x8 b0 = *(const bf16x8*)(Bb + kt * 32);
        bf16x8 b1 = *(const bf16x8*)(Bb + 16 * LDL + kt * 32);
        acc00 = __builtin_amdgcn_mfma_f32_16x16x32_bf16(a0, b0, acc00, 0, 0, 0);
        acc01 = __builtin_amdgcn_mfma_f32_16x16x32_bf16(a0, b1, acc01, 0, 0, 0);
        acc10 = __builtin_amdgcn_mfma_f32_16x16x32_bf16(a1, b0, acc10, 0, 0, 0);
        acc11 = __builtin_amdgcn_mfma_f32_16x16x32_bf16(a1, b1, acc11, 0, 0, 0);
    }
    // Epilogue. C/D layout: col = lane&15, row = (lane>>4)*4 + reg.
    f32x4 accs[2][2] = {{acc00, acc01}, {acc10, acc11}};
#pragma unroll
    for (int m = 0; m < 2; ++m) {
#pragma unroll
        for (int n = 0; n < 2; ++n) {
            int col = bn + wc * 32 + n * 16 + ln;
            float bv = bias[col];
#pragma unroll
            for (int r = 0; r < 4; ++r) {
                int row = bm + wr * 32 + m * 16 + kh * 4 + r;
                float v = accs[m][n][r] + bv;
                if (RELU) v = fmaxf(v, 0.f);
                if (OUTF32) {
                    if (col < ncols) ((float*)Cout)[(size_t)row * ncols + col] = v;
                } else {
                    ((ushort*)Cout)[(size_t)row * ldc + col] = f2bf(v);
                }
            }
        }
    }
}

// ---------------------------------------------------------------------------

static inline char* carve(char*& p, size_t bytes) {
    char* r = p;
    p += (bytes + 255) & ~(size_t)255;
    return r;
}

extern "C" void kernel_launch(void* const* d_in, const int* in_sizes, int n_in,
                              void* d_out, int out_size, void* d_ws, size_t ws_size,
                              hipStream_t stream) {
    const float* x        = (const float*)d_in[0];
    const int*   src1     = (const int*)d_in[1];
    const int*   dst1     = (const int*)d_in[2];
    const int*   src2     = (const int*)d_in[3];
    const int*   dst2     = (const int*)d_in[4];
    const float* W_self1  = (const float*)d_in[7];
    const float* W_neigh1 = (const float*)d_in[8];
    const float* b1       = (const float*)d_in[9];
    const float* W_self2  = (const float*)d_in[10];
    const float* W_neigh2 = (const float*)d_in[11];
    const float* b2       = (const float*)d_in[12];
    float* out = (float*)d_out;

    const int E1 = in_sizes[1];
    const int E2 = in_sizes[3];

    char* p = (char*)d_ws;
    ushort* xb       = (ushort*)carve(p, (size_t)N1_SRC * IN_F * 2);   // 51.2 MB
    ushort* hb       = (ushort*)carve(p, (size_t)N2_DST * H_F * 2);    // 20.5 MB
    ushort* hneighb  = (ushort*)carve(p, (size_t)N2_DST * IN_F * 2);   // 10.2 MB
    ushort* hneigh2b = (ushort*)carve(p, (size_t)N3_DST * H_F * 2);    //  4.1 MB
    int*    edges    = (int*)carve(p, (size_t)E1 * 4);                 //  5.1 MB
    int*    counts   = (int*)carve(p, (size_t)N2_DST * 4);
    int*    offsets  = (int*)carve(p, (size_t)(N2_DST + 1) * 4);
    int*    cursor   = (int*)carve(p, (size_t)N2_DST * 4);
    int*    bsum     = (int*)carve(p, 256 * 4);
    ushort* WT1      = (ushort*)carve(p, (size_t)H_F * (IN_F * 2) * 2);  // 256x256 bf16
    ushort* WT2      = (ushort*)carve(p, (size_t)64 * (H_F * 2) * 2);    // 64x512 bf16
    float*  bias2p   = (float*)carve(p, 64 * 4);

    // --- one-time-per-call prep (cheap) ---
    {
        int n4 = N1_SRC * IN_F / 4;
        cast_f32_to_bf16<<<(n4 + 255) / 256, 256, 0, stream>>>(x, xb, n4);
        build_wt<<<H_F, 256, 0, stream>>>(W_self1, W_neigh1, WT1, H_F, IN_F, IN_F);
        build_wt<<<64, 256, 0, stream>>>(W_self2, W_neigh2, WT2, C_F, H_F, H_F);
        pad_bias<<<1, 64, 0, stream>>>(b2, bias2p, C_F, 64);
    }

    // ---------------- Layer 1 ----------------
    {
        hipMemsetAsync(counts, 0, (size_t)N2_DST * 4, stream);
        hipMemsetAsync(cursor, 0, (size_t)N2_DST * 4, stream);
        hist_kernel<<<(E1 + 255) / 256, 256, 0, stream>>>(dst1, counts, E1);
        int nb = (N2_DST + SCAN_CHUNK - 1) / SCAN_CHUNK;  // 40
        scan_phase1<<<nb, 256, 0, stream>>>(counts, offsets, bsum, N2_DST);
        scan_phase2<<<1, 256, 0, stream>>>(bsum, nb, offsets + N2_DST, E1);
        scan_phase3<<<nb, 256, 0, stream>>>(offsets, bsum, N2_DST);
        fill_kernel<<<(E1 + 255) / 256, 256, 0, stream>>>(src1, dst1, offsets, cursor, edges, E1);
        gather_mean_f128<<<N2_DST / 4, 256, 0, stream>>>(xb, edges, offsets, hneighb);
        dim3 grid(H_F / 64, N2_DST / 64);  // 4 x 625
        sage_mfma_gemm<256, 128, true, false><<<grid, 256, 0, stream>>>(
            xb, hneighb, WT1, b1, hb, H_F, H_F);
    }

    // ---------------- Layer 2 ----------------
    {
        hipMemsetAsync(counts, 0, (size_t)N3_DST * 4, stream);
        hipMemsetAsync(cursor, 0, (size_t)N3_DST * 4, stream);
        hist_kernel<<<(E2 + 255) / 256, 256, 0, stream>>>(dst2, counts, E2);
        int nb = (N3_DST + SCAN_CHUNK - 1) / SCAN_CHUNK;  // 8
        scan_phase1<<<nb, 256, 0, stream>>>(counts, offsets, bsum, N3_DST);
        scan_phase2<<<1, 256, 0, stream>>>(bsum, nb, offsets + N3_DST, E2);
        scan_phase3<<<nb, 256, 0, stream>>>(offsets, bsum, N3_DST);
        fill_kernel<<<(E2 + 255) / 256, 256, 0, stream>>>(src2, dst2, offsets, cursor, edges, E2);
        gather_mean_f256<<<N3_DST / 4, 256, 0, stream>>>(hb, edges, offsets, hneigh2b);
        dim3 grid(1, N3_DST / 64);  // 1 x 125
        sage_mfma_gemm<512, 256, false, true><<<grid, 256, 0, stream>>>(
            hb, hneigh2b, WT2, bias2p, out, C_F, C_F);
    }
}

// Round 6
// 266.875 us; speedup vs baseline: 13.0727x; 1.1186x over previous
//
#include <hip/hip_runtime.h>
#include <hip/hip_bf16.h>
#include <cstddef>

// ---------------------------------------------------------------------------
// SAGE 2-layer, bf16/MFMA edition, wave-per-dst ILP gathers, and CSR build via
// two-level binned counting sort (no scattered-4B cross-XCD writes).
// Pipeline per layer: hist + scan -> bin_pass1 (coarse bucket, per-block run
// reservation) -> bin_pass2 (exact per-dst placement, block-contiguous writes)
// -> bf16 gather-mean -> fused dual GEMM as single MFMA GEMM:
//      C = [A_self | A_neigh] @ [W_self ; W_neigh] + b
// Sizes fixed: N1=200000, N2=40000, N3=8000, E1=1280000, E2=256000,
// IN=128, H=256, C=47.
// ---------------------------------------------------------------------------

#define N1_SRC 200000
#define N2_DST 40000
#define N3_DST 8000
#define IN_F 128
#define H_F 256
#define C_F 47

typedef short bf16x8 __attribute__((ext_vector_type(8)));
typedef float f32x4 __attribute__((ext_vector_type(4)));

__device__ __forceinline__ float bf2f(ushort u) {
    union { uint i; float f; } v; v.i = ((uint)u) << 16; return v.f;
}
__device__ __forceinline__ ushort f2bf(float f) {
    union { float f; uint i; } v; v.f = f;
    uint r = v.i + 0x7FFF + ((v.i >> 16) & 1);
    return (ushort)(r >> 16);
}

// --- bf16 cast of x ---------------------------------------------------------

__global__ void cast_f32_to_bf16(const float* __restrict__ in,
                                 ushort* __restrict__ out, int n4) {
    int i = blockIdx.x * blockDim.x + threadIdx.x;
    if (i >= n4) return;
    float4 v = ((const float4*)in)[i];
    ushort4 o;
    o.x = f2bf(v.x); o.y = f2bf(v.y); o.z = f2bf(v.z); o.w = f2bf(v.w);
    ((ushort4*)out)[i] = o;
}

// --- weight prep: WT[n][k] = bf16( k<KS ? Wself[k][n] : Wneigh[k-KS][n] ), pad n>=N with 0

__global__ void build_wt(const float* __restrict__ Wself, const float* __restrict__ Wneigh,
                         ushort* __restrict__ WT, int N, int KS, int KN) {
    int n = blockIdx.x;
    int K = KS + KN;
    for (int k = threadIdx.x; k < K; k += blockDim.x) {
        float v = 0.f;
        if (n < N) v = (k < KS) ? Wself[(size_t)k * N + n] : Wneigh[(size_t)(k - KS) * N + n];
        WT[(size_t)n * K + k] = f2bf(v);
    }
}

__global__ void pad_bias(const float* __restrict__ b, float* __restrict__ bp, int n, int np) {
    int i = threadIdx.x;
    if (i < np) bp[i] = (i < n) ? b[i] : 0.f;
}

// --- CSR build: hist + 3-phase scan -----------------------------------------

__global__ void hist_kernel(const int* __restrict__ dst, int* __restrict__ counts, int E) {
    int e = blockIdx.x * blockDim.x + threadIdx.x;
    if (e < E) atomicAdd(&counts[dst[e]], 1);
}

#define SCAN_CHUNK 1024
__global__ void scan_phase1(const int* __restrict__ counts, int* __restrict__ pre,
                            int* __restrict__ bsum, int n) {
    __shared__ int smem[256];
    int b = blockIdx.x, t = threadIdx.x;
    int base = b * SCAN_CHUNK + t * 4;
    int v0 = 0, v1 = 0, v2 = 0, v3 = 0;
    if (base + 3 < n) {
        int4 c = *(const int4*)&counts[base];
        v0 = c.x; v1 = c.y; v2 = c.z; v3 = c.w;
    } else {
        if (base + 0 < n) v0 = counts[base + 0];
        if (base + 1 < n) v1 = counts[base + 1];
        if (base + 2 < n) v2 = counts[base + 2];
        if (base + 3 < n) v3 = counts[base + 3];
    }
    int s = v0 + v1 + v2 + v3;
    smem[t] = s;
    __syncthreads();
    for (int off = 1; off < 256; off <<= 1) {
        int tv = (t >= off) ? smem[t - off] : 0;
        __syncthreads();
        smem[t] += tv;
        __syncthreads();
    }
    int excl = smem[t] - s;
    int p0 = excl, p1 = p0 + v0, p2 = p1 + v1, p3 = p2 + v2;
    if (base + 3 < n) {
        *(int4*)&pre[base] = make_int4(p0, p1, p2, p3);
    } else {
        if (base + 0 < n) pre[base + 0] = p0;
        if (base + 1 < n) pre[base + 1] = p1;
        if (base + 2 < n) pre[base + 2] = p2;
        if (base + 3 < n) pre[base + 3] = p3;
    }
    if (t == 255) bsum[b] = smem[255];
}

__global__ void scan_phase2(int* __restrict__ bsum, int nb, int* __restrict__ off_end, int E) {
    __shared__ int smem[256];
    int t = threadIdx.x;
    int v = (t < nb) ? bsum[t] : 0;
    smem[t] = v;
    __syncthreads();
    for (int off = 1; off < 256; off <<= 1) {
        int tv = (t >= off) ? smem[t - off] : 0;
        __syncthreads();
        smem[t] += tv;
        __syncthreads();
    }
    if (t < nb) bsum[t] = smem[t] - v;
    if (t == 0) *off_end = E;
}

__global__ void scan_phase3(int* __restrict__ pre, const int* __restrict__ bsum, int n) {
    int b = blockIdx.x, t = threadIdx.x;
    int base = b * SCAN_CHUNK + t * 4;
    int add = bsum[b];
    if (base + 3 < n) {
        int4 c = *(int4*)&pre[base];
        c.x += add; c.y += add; c.z += add; c.w += add;
        *(int4*)&pre[base] = c;
    } else {
        if (base + 0 < n) pre[base + 0] += add;
        if (base + 1 < n) pre[base + 1] += add;
        if (base + 2 < n) pre[base + 2] += add;
    }
}

// --- Two-level binned sort (replaces scattered fill) ------------------------
// gcursor[b] starts at offsets[b<<SHIFT]; pass1 bins edges into coarse-bucket
// runs reserved per block (one CU writes each run -> L2 write-combining);
// pass2 places each bucket's edges at exact per-dst positions, with the whole
// block output span contiguous.

__global__ void init_gcursor(const int* __restrict__ offsets, int* __restrict__ gcursor,
                             int nb, int shift) {
    int b = blockIdx.x * blockDim.x + threadIdx.x;
    if (b < nb) gcursor[b] = offsets[b << shift];
}

template <int NB, int SHIFT, int SRCB, int EPB>
__global__ __launch_bounds__(256) void bin_pass1(
    const int* __restrict__ src, const int* __restrict__ dst,
    int* __restrict__ gcursor, uint* __restrict__ temp, int E) {
    __shared__ int cnt[NB];
    __shared__ int rnk[NB];
    __shared__ int gbase[NB];
    int t = threadIdx.x;
    int e0 = blockIdx.x * EPB;
    for (int i = t; i < NB; i += 256) { cnt[i] = 0; rnk[i] = 0; }
    __syncthreads();
#pragma unroll
    for (int i = 0; i < EPB / 256; ++i) {
        int e = e0 + i * 256 + t;
        if (e < E) atomicAdd(&cnt[dst[e] >> SHIFT], 1);
    }
    __syncthreads();
    for (int b = t; b < NB; b += 256) {
        int c = cnt[b];
        gbase[b] = c ? atomicAdd(&gcursor[b], c) : 0;
    }
    __syncthreads();
#pragma unroll
    for (int i = 0; i < EPB / 256; ++i) {
        int e = e0 + i * 256 + t;
        if (e < E) {
            int d = dst[e];
            int b = d >> SHIFT;
            int r = atomicAdd(&rnk[b], 1);
            uint val = ((uint)(d & ((1 << SHIFT) - 1)) << SRCB) | (uint)src[e];
            temp[gbase[b] + r] = val;
        }
    }
}

template <int SHIFT, int SRCB>
__global__ __launch_bounds__(256) void bin_pass2(
    const uint* __restrict__ temp, const int* __restrict__ offsets,
    int* __restrict__ edges, int nd) {
    constexpr int DPB = 1 << SHIFT;
    __shared__ int rnk[DPB];
    __shared__ int obase[DPB];
    int b = blockIdx.x, t = threadIdx.x;
    int dbase = b << SHIFT;
    for (int i = t; i < DPB; i += 256) {
        rnk[i] = 0;
        obase[i] = (dbase + i < nd) ? offsets[dbase + i] : 0;
    }
    __syncthreads();
    int beg = offsets[dbase];
    int dend = dbase + DPB; if (dend > nd) dend = nd;
    int end = offsets[dend];
    for (int i = beg + t; i < end; i += 256) {
        uint v = temp[i];
        int dlow = (int)(v >> SRCB);
        int s = (int)(v & ((1u << SRCB) - 1));
        int r = atomicAdd(&rnk[dlow], 1);
        edges[obase[dlow] + r] = s;
    }
}

// --- Wave-per-dst bf16 gather-mean, deep ILP, no LDS / no barriers ----------
// f128: 64 lanes x 4 B (uint = 2 bf16) = one 256 B row; lane owns its 2 feats.

__global__ __launch_bounds__(256) void gather_mean_f128(
    const ushort* __restrict__ xb, const int* __restrict__ edges,
    const int* __restrict__ offsets, ushort* __restrict__ outb) {
    int d = (blockIdx.x << 2) | (threadIdx.x >> 6);   // wave-per-dst, 4 waves/block
    int lane = threadIdx.x & 63;
    int beg = offsets[d], end = offsets[d + 1];
    float sx = 0.f, sy = 0.f;
    int i = beg;
    for (; i + 7 < end; i += 8) {
        int e0 = edges[i + 0], e1 = edges[i + 1], e2 = edges[i + 2], e3 = edges[i + 3];
        int e4 = edges[i + 4], e5 = edges[i + 5], e6 = edges[i + 6], e7 = edges[i + 7];
        uint v0 = ((const uint*)(xb + (size_t)e0 * IN_F))[lane];
        uint v1 = ((const uint*)(xb + (size_t)e1 * IN_F))[lane];
        uint v2 = ((const uint*)(xb + (size_t)e2 * IN_F))[lane];
        uint v3 = ((const uint*)(xb + (size_t)e3 * IN_F))[lane];
        uint v4 = ((const uint*)(xb + (size_t)e4 * IN_F))[lane];
        uint v5 = ((const uint*)(xb + (size_t)e5 * IN_F))[lane];
        uint v6 = ((const uint*)(xb + (size_t)e6 * IN_F))[lane];
        uint v7 = ((const uint*)(xb + (size_t)e7 * IN_F))[lane];
        sx += bf2f((ushort)(v0 & 0xffff)); sy += bf2f((ushort)(v0 >> 16));
        sx += bf2f((ushort)(v1 & 0xffff)); sy += bf2f((ushort)(v1 >> 16));
        sx += bf2f((ushort)(v2 & 0xffff)); sy += bf2f((ushort)(v2 >> 16));
        sx += bf2f((ushort)(v3 & 0xffff)); sy += bf2f((ushort)(v3 >> 16));
        sx += bf2f((ushort)(v4 & 0xffff)); sy += bf2f((ushort)(v4 >> 16));
        sx += bf2f((ushort)(v5 & 0xffff)); sy += bf2f((ushort)(v5 >> 16));
        sx += bf2f((ushort)(v6 & 0xffff)); sy += bf2f((ushort)(v6 >> 16));
        sx += bf2f((ushort)(v7 & 0xffff)); sy += bf2f((ushort)(v7 >> 16));
    }
    for (; i < end; ++i) {
        uint v = ((const uint*)(xb + (size_t)edges[i] * IN_F))[lane];
        sx += bf2f((ushort)(v & 0xffff));
        sy += bf2f((ushort)(v >> 16));
    }
    float inv = 1.0f / fmaxf((float)(end - beg), 1.0f);
    ((uint*)(outb + (size_t)d * IN_F))[lane] =
        (uint)f2bf(sx * inv) | ((uint)f2bf(sy * inv) << 16);
}

// f256: 64 lanes x 8 B (uint2 = 4 bf16) = one 512 B row; lane owns 4 feats.
__global__ __launch_bounds__(256) void gather_mean_f256(
    const ushort* __restrict__ hb, const int* __restrict__ edges,
    const int* __restrict__ offsets, ushort* __restrict__ outb) {
    int d = (blockIdx.x << 2) | (threadIdx.x >> 6);
    int lane = threadIdx.x & 63;
    int beg = offsets[d], end = offsets[d + 1];
    float s0 = 0.f, s1 = 0.f, s2 = 0.f, s3 = 0.f;
    int i = beg;
    for (; i + 3 < end; i += 4) {
        int e0 = edges[i + 0], e1 = edges[i + 1], e2 = edges[i + 2], e3 = edges[i + 3];
        uint2 v0 = ((const uint2*)(hb + (size_t)e0 * H_F))[lane];
        uint2 v1 = ((const uint2*)(hb + (size_t)e1 * H_F))[lane];
        uint2 v2 = ((const uint2*)(hb + (size_t)e2 * H_F))[lane];
        uint2 v3 = ((const uint2*)(hb + (size_t)e3 * H_F))[lane];
        s0 += bf2f((ushort)(v0.x & 0xffff)); s1 += bf2f((ushort)(v0.x >> 16));
        s2 += bf2f((ushort)(v0.y & 0xffff)); s3 += bf2f((ushort)(v0.y >> 16));
        s0 += bf2f((ushort)(v1.x & 0xffff)); s1 += bf2f((ushort)(v1.x >> 16));
        s2 += bf2f((ushort)(v1.y & 0xffff)); s3 += bf2f((ushort)(v1.y >> 16));
        s0 += bf2f((ushort)(v2.x & 0xffff)); s1 += bf2f((ushort)(v2.x >> 16));
        s2 += bf2f((ushort)(v2.y & 0xffff)); s3 += bf2f((ushort)(v2.y >> 16));
        s0 += bf2f((ushort)(v3.x & 0xffff)); s1 += bf2f((ushort)(v3.x >> 16));
        s2 += bf2f((ushort)(v3.y & 0xffff)); s3 += bf2f((ushort)(v3.y >> 16));
    }
    for (; i < end; ++i) {
        uint2 v = ((const uint2*)(hb + (size_t)edges[i] * H_F))[lane];
        s0 += bf2f((ushort)(v.x & 0xffff)); s1 += bf2f((ushort)(v.x >> 16));
        s2 += bf2f((ushort)(v.y & 0xffff)); s3 += bf2f((ushort)(v.y >> 16));
    }
    float inv = 1.0f / fmaxf((float)(end - beg), 1.0f);
    uint2 o;
    o.x = (uint)f2bf(s0 * inv) | ((uint)f2bf(s1 * inv) << 16);
    o.y = (uint)f2bf(s2 * inv) | ((uint)f2bf(s3 * inv) << 16);
    ((uint2*)(outb + (size_t)d * H_F))[lane] = o;
}

// --- MFMA GEMM: C = (relu?)([Aself|Aneigh] @ WT^T + bias) -------------------
// Block tile 64x64, 4 waves (2x2), each wave 32x32 via 2x2 frags of 16x16x32.

template <int K, int KSELF, bool RELU, bool OUTF32>
__global__ __launch_bounds__(256) void sage_mfma_gemm(
    const ushort* __restrict__ Aself, const ushort* __restrict__ Aneigh,
    const ushort* __restrict__ WT, const float* __restrict__ bias,
    void* __restrict__ Cout, int ldc, int ncols) {
    constexpr int KN = K - KSELF;
    constexpr int LDL = K + 8;  // LDS row stride in elems (+16B pad: 2-way conflicts only)
    __shared__ __align__(16) ushort A_lds[64 * LDL];
    __shared__ __align__(16) ushort B_lds[64 * LDL];
    int t = threadIdx.x;
    int bn = blockIdx.x * 64, bm = blockIdx.y * 64;
    constexpr int CPR = K / 8;            // 16B chunks per row
    constexpr int ITER = 64 * CPR / 256;  // staging iterations
#pragma unroll
    for (int c = 0; c < ITER; ++c) {
        int id = c * 256 + t;
        int row = id / CPR;
        int kc = (id % CPR) * 8;
        const ushort* sa = (kc < KSELF)
                               ? Aself + (size_t)(bm + row) * KSELF + kc
                               : Aneigh + (size_t)(bm + row) * KN + (kc - KSELF);
        float4 av = *(const float4*)sa;
        float4 bv = *(const float4*)(WT + (size_t)(bn + row) * K + kc);
        *(float4*)&A_lds[row * LDL + kc] = av;
        *(float4*)&B_lds[row * LDL + kc] = bv;
    }
    __syncthreads();
    int lane = t & 63, w = t >> 6;
    int wr = w >> 1, wc = w & 1;
    int ln = lane & 15, kh = lane >> 4;
    const ushort* Ab = &A_lds[(wr * 32 + ln) * LDL + kh * 8];
    const ushort* Bb = &B_lds[(wc * 32 + ln) * LDL + kh * 8];
    f32x4 acc00 = {0.f, 0.f, 0.f, 0.f};
    f32x4 acc01 = {0.f, 0.f, 0.f, 0.f};
    f32x4 acc10 = {0.f, 0.f, 0.f, 0.f};
    f32x4 acc11 = {0.f, 0.f, 0.f, 0.f};
#pragma unroll
    for (int kt = 0; kt < K / 32; ++kt) {
        bf16x8 a0 = *(const bf16x8*)(Ab + kt * 32);
        bf16x8 a1 = *(const bf16x8*)(Ab + 16 * LDL + kt * 32);
        bf16x8 b0 = *(const bf16x8*)(Bb + kt * 32);
        bf16x8 b1 = *(const bf16x8*)(Bb + 16 * LDL + kt * 32);
        acc00 = __builtin_amdgcn_mfma_f32_16x16x32_bf16(a0, b0, acc00, 0, 0, 0);
        acc01 = __builtin_amdgcn_mfma_f32_16x16x32_bf16(a0, b1, acc01, 0, 0, 0);
        acc10 = __builtin_amdgcn_mfma_f32_16x16x32_bf16(a1, b0, acc10, 0, 0, 0);
        acc11 = __builtin_amdgcn_mfma_f32_16x16x32_bf16(a1, b1, acc11, 0, 0, 0);
    }
    // Epilogue. C/D layout: col = lane&15, row = (lane>>4)*4 + reg.
    f32x4 accs[2][2] = {{acc00, acc01}, {acc10, acc11}};
#pragma unroll
    for (int m = 0; m < 2; ++m) {
#pragma unroll
        for (int n = 0; n < 2; ++n) {
            int col = bn + wc * 32 + n * 16 + ln;
            float bv = bias[col];
#pragma unroll
            for (int r = 0; r < 4; ++r) {
                int row = bm + wr * 32 + m * 16 + kh * 4 + r;
                float v = accs[m][n][r] + bv;
                if (RELU) v = fmaxf(v, 0.f);
                if (OUTF32) {
                    if (col < ncols) ((float*)Cout)[(size_t)row * ncols + col] = v;
                } else {
                    ((ushort*)Cout)[(size_t)row * ldc + col] = f2bf(v);
                }
            }
        }
    }
}

// ---------------------------------------------------------------------------

static inline char* carve(char*& p, size_t bytes) {
    char* r = p;
    p += (bytes + 255) & ~(size_t)255;
    return r;
}

extern "C" void kernel_launch(void* const* d_in, const int* in_sizes, int n_in,
                              void* d_out, int out_size, void* d_ws, size_t ws_size,
                              hipStream_t stream) {
    const float* x        = (const float*)d_in[0];
    const int*   src1     = (const int*)d_in[1];
    const int*   dst1     = (const int*)d_in[2];
    const int*   src2     = (const int*)d_in[3];
    const int*   dst2     = (const int*)d_in[4];
    const float* W_self1  = (const float*)d_in[7];
    const float* W_neigh1 = (const float*)d_in[8];
    const float* b1       = (const float*)d_in[9];
    const float* W_self2  = (const float*)d_in[10];
    const float* W_neigh2 = (const float*)d_in[11];
    const float* b2       = (const float*)d_in[12];
    float* out = (float*)d_out;

    const int E1 = in_sizes[1];
    const int E2 = in_sizes[3];

    // Coarse-bucket parameters
    constexpr int SHIFT1 = 7, NB1 = (N2_DST + 127) >> 7, SRCB1 = 18;  // 313 buckets
    constexpr int SHIFT2 = 6, NB2 = (N3_DST + 63) >> 6, SRCB2 = 16;   // 125 buckets

    char* p = (char*)d_ws;
    ushort* xb       = (ushort*)carve(p, (size_t)N1_SRC * IN_F * 2);   // 51.2 MB
    ushort* hb       = (ushort*)carve(p, (size_t)N2_DST * H_F * 2);    // 20.5 MB
    ushort* hneighb  = (ushort*)carve(p, (size_t)N2_DST * IN_F * 2);   // 10.2 MB
    ushort* hneigh2b = (ushort*)carve(p, (size_t)N3_DST * H_F * 2);    //  4.1 MB
    int*    edges    = (int*)carve(p, (size_t)E1 * 4);                 //  5.1 MB
    int*    counts   = (int*)carve(p, (size_t)N2_DST * 4);
    int*    offsets  = (int*)carve(p, (size_t)(N2_DST + 1) * 4);
    int*    gcursor  = (int*)carve(p, (size_t)NB1 * 4);
    int*    bsum     = (int*)carve(p, 256 * 4);
    ushort* WT1      = (ushort*)carve(p, (size_t)H_F * (IN_F * 2) * 2);  // 256x256 bf16
    ushort* WT2      = (ushort*)carve(p, (size_t)64 * (H_F * 2) * 2);    // 64x512 bf16
    float*  bias2p   = (float*)carve(p, 64 * 4);
    // temp (binned packed edges) aliases hneighb: liveness is disjoint
    // (temp: pass1->pass2; hneighb: gather->GEMM, which follow pass2).
    uint* temp = (uint*)hneighb;

    // --- one-time-per-call prep (cheap) ---
    {
        int n4 = N1_SRC * IN_F / 4;
        cast_f32_to_bf16<<<(n4 + 255) / 256, 256, 0, stream>>>(x, xb, n4);
        build_wt<<<H_F, 256, 0, stream>>>(W_self1, W_neigh1, WT1, H_F, IN_F, IN_F);
        build_wt<<<64, 256, 0, stream>>>(W_self2, W_neigh2, WT2, C_F, H_F, H_F);
        pad_bias<<<1, 64, 0, stream>>>(b2, bias2p, C_F, 64);
    }

    // ---------------- Layer 1 ----------------
    {
        hipMemsetAsync(counts, 0, (size_t)N2_DST * 4, stream);
        hist_kernel<<<(E1 + 255) / 256, 256, 0, stream>>>(dst1, counts, E1);
        int nb = (N2_DST + SCAN_CHUNK - 1) / SCAN_CHUNK;  // 40
        scan_phase1<<<nb, 256, 0, stream>>>(counts, offsets, bsum, N2_DST);
        scan_phase2<<<1, 256, 0, stream>>>(bsum, nb, offsets + N2_DST, E1);
        scan_phase3<<<nb, 256, 0, stream>>>(offsets, bsum, N2_DST);
        init_gcursor<<<(NB1 + 255) / 256, 256, 0, stream>>>(offsets, gcursor, NB1, SHIFT1);
        bin_pass1<NB1, SHIFT1, SRCB1, 4096><<<(E1 + 4095) / 4096, 256, 0, stream>>>(
            src1, dst1, gcursor, temp, E1);
        bin_pass2<SHIFT1, SRCB1><<<NB1, 256, 0, stream>>>(temp, offsets, edges, N2_DST);
        gather_mean_f128<<<N2_DST / 4, 256, 0, stream>>>(xb, edges, offsets, hneighb);
        dim3 grid(H_F / 64, N2_DST / 64);  // 4 x 625
        sage_mfma_gemm<256, 128, true, false><<<grid, 256, 0, stream>>>(
            xb, hneighb, WT1, b1, hb, H_F, H_F);
    }

    // ---------------- Layer 2 ----------------
    {
        hipMemsetAsync(counts, 0, (size_t)N3_DST * 4, stream);
        hist_kernel<<<(E2 + 255) / 256, 256, 0, stream>>>(dst2, counts, E2);
        int nb = (N3_DST + SCAN_CHUNK - 1) / SCAN_CHUNK;  // 8
        scan_phase1<<<nb, 256, 0, stream>>>(counts, offsets, bsum, N3_DST);
        scan_phase2<<<1, 256, 0, stream>>>(bsum, nb, offsets + N3_DST, E2);
        scan_phase3<<<nb, 256, 0, stream>>>(offsets, bsum, N3_DST);
        init_gcursor<<<(NB2 + 255) / 256, 256, 0, stream>>>(offsets, gcursor, NB2, SHIFT2);
        bin_pass1<NB2, SHIFT2, SRCB2, 2048><<<(E2 + 2047) / 2048, 256, 0, stream>>>(
            src2, dst2, gcursor, temp, E2);
        bin_pass2<SHIFT2, SRCB2><<<NB2, 256, 0, stream>>>(temp, offsets, edges, N3_DST);
        gather_mean_f256<<<N3_DST / 4, 256, 0, stream>>>(hb, edges, offsets, hneigh2b);
        dim3 grid(1, N3_DST / 64);  // 1 x 125
        sage_mfma_gemm<512, 256, false, true><<<grid, 256, 0, stream>>>(
            hb, hneigh2b, WT2, bias2p, out, C_F, C_F);
    }
}

// Round 7
// 211.259 us; speedup vs baseline: 16.5143x; 1.2633x over previous
//
#include <hip/hip_runtime.h>
#include <hip/hip_bf16.h>
#include <cstddef>

// ---------------------------------------------------------------------------
// SAGE 2-layer, bf16/MFMA edition.
// CSR build: coarse bucket_hist (LDS-privatized) + bucket scan -> bin_pass1
// (bucket runs, per-block reservation) -> bin_pass2 (per-dst offsets computed
// in-block from bucket data; writes offsets[] for gather; block-contiguous
// edge placement). No per-dst global histogram at all.
// Then: wave-per-dst bf16 gather-mean -> fused dual GEMM as one MFMA GEMM:
//      C = [A_self | A_neigh] @ [W_self ; W_neigh] + b
// Sizes fixed: N1=200000, N2=40000, N3=8000, E1=1280000, E2=256000,
// IN=128, H=256, C=47.
// ---------------------------------------------------------------------------

#define N1_SRC 200000
#define N2_DST 40000
#define N3_DST 8000
#define IN_F 128
#define H_F 256
#define C_F 47

typedef short bf16x8 __attribute__((ext_vector_type(8)));
typedef float f32x4 __attribute__((ext_vector_type(4)));

__device__ __forceinline__ float bf2f(ushort u) {
    union { uint i; float f; } v; v.i = ((uint)u) << 16; return v.f;
}
__device__ __forceinline__ ushort f2bf(float f) {
    union { float f; uint i; } v; v.f = f;
    uint r = v.i + 0x7FFF + ((v.i >> 16) & 1);
    return (ushort)(r >> 16);
}

// --- bf16 cast of x ---------------------------------------------------------

__global__ void cast_f32_to_bf16(const float* __restrict__ in,
                                 ushort* __restrict__ out, int n4) {
    int i = blockIdx.x * blockDim.x + threadIdx.x;
    if (i >= n4) return;
    float4 v = ((const float4*)in)[i];
    ushort4 o;
    o.x = f2bf(v.x); o.y = f2bf(v.y); o.z = f2bf(v.z); o.w = f2bf(v.w);
    ((ushort4*)out)[i] = o;
}

// --- weight prep: WT[n][k] = bf16( k<KS ? Wself[k][n] : Wneigh[k-KS][n] ), pad n>=N with 0

__global__ void build_wt(const float* __restrict__ Wself, const float* __restrict__ Wneigh,
                         ushort* __restrict__ WT, int N, int KS, int KN) {
    int n = blockIdx.x;
    int K = KS + KN;
    for (int k = threadIdx.x; k < K; k += blockDim.x) {
        float v = 0.f;
        if (n < N) v = (k < KS) ? Wself[(size_t)k * N + n] : Wneigh[(size_t)(k - KS) * N + n];
        WT[(size_t)n * K + k] = f2bf(v);
    }
}

__global__ void pad_bias(const float* __restrict__ b, float* __restrict__ bp, int n, int np) {
    int i = threadIdx.x;
    if (i < np) bp[i] = (i < n) ? b[i] : 0.f;
}

// --- Coarse bucket hist: LDS-privatized, NB counters only -------------------

template <int NB, int SHIFT, int EPT>
__global__ __launch_bounds__(256) void bucket_hist(const int* __restrict__ dst,
                                                   int* __restrict__ bcnt, int E) {
    __shared__ int cnt[NB];
    for (int i = threadIdx.x; i < NB; i += 256) cnt[i] = 0;
    __syncthreads();
    int base = blockIdx.x * 256 * EPT + threadIdx.x;
#pragma unroll
    for (int i = 0; i < EPT; ++i) {
        int e = base + i * 256;
        if (e < E) atomicAdd(&cnt[dst[e] >> SHIFT], 1);
    }
    __syncthreads();
    for (int i = threadIdx.x; i < NB; i += 256) {
        int c = cnt[i];
        if (c) atomicAdd(&bcnt[i], c);
    }
}

// Single-block exclusive scan of nb (<512) bucket counts -> boff; boff[nb]=E;
// also writes offsets[nd]=E (needed by gather for the last dst).
__global__ void bucket_scan(const int* __restrict__ bcnt, int* __restrict__ boff,
                            int nb, int E, int* __restrict__ offsets, int nd) {
    __shared__ int smem[512];
    int t = threadIdx.x;
    int v = (t < nb) ? bcnt[t] : 0;
    smem[t] = v;
    __syncthreads();
    for (int off = 1; off < 512; off <<= 1) {
        int tv = (t >= off) ? smem[t - off] : 0;
        __syncthreads();
        smem[t] += tv;
        __syncthreads();
    }
    if (t < nb) boff[t] = smem[t] - v;
    if (t == 0) { boff[nb] = E; offsets[nd] = E; }
}

// --- Two-level binned sort ---------------------------------------------------
// pass1: bin edges into coarse-bucket runs reserved per block (one CU writes
// each run -> L2 write-combining). temp value = (dlow << SRCB) | src.

template <int NB, int SHIFT, int SRCB, int EPB>
__global__ __launch_bounds__(256) void bin_pass1(
    const int* __restrict__ src, const int* __restrict__ dst,
    int* __restrict__ gcursor, uint* __restrict__ temp, int E) {
    __shared__ int cnt[NB];
    __shared__ int rnk[NB];
    __shared__ int gbase[NB];
    int t = threadIdx.x;
    int e0 = blockIdx.x * EPB;
    for (int i = t; i < NB; i += 256) { cnt[i] = 0; rnk[i] = 0; }
    __syncthreads();
#pragma unroll
    for (int i = 0; i < EPB / 256; ++i) {
        int e = e0 + i * 256 + t;
        if (e < E) atomicAdd(&cnt[dst[e] >> SHIFT], 1);
    }
    __syncthreads();
    for (int b = t; b < NB; b += 256) {
        int c = cnt[b];
        gbase[b] = c ? atomicAdd(&gcursor[b], c) : 0;
    }
    __syncthreads();
#pragma unroll
    for (int i = 0; i < EPB / 256; ++i) {
        int e = e0 + i * 256 + t;
        if (e < E) {
            int d = dst[e];
            int b = d >> SHIFT;
            int r = atomicAdd(&rnk[b], 1);
            uint val = ((uint)(d & ((1 << SHIFT) - 1)) << SRCB) | (uint)src[e];
            temp[gbase[b] + r] = val;
        }
    }
}

// pass2: per coarse bucket, count dlow in LDS, local exclusive scan -> per-dst
// offsets (written globally for the gather), then place edges contiguously.
template <int SHIFT, int SRCB>
__global__ __launch_bounds__(256) void bin_pass2(
    const uint* __restrict__ temp, const int* __restrict__ boff,
    int* __restrict__ offsets, int* __restrict__ edges, int nd) {
    constexpr int DPB = 1 << SHIFT;
    __shared__ int cnt[DPB];
    __shared__ int scn[DPB];
    __shared__ int obase[DPB];
    __shared__ int rnk[DPB];
    int b = blockIdx.x, t = threadIdx.x;
    int dbase = b << SHIFT;
    for (int i = t; i < DPB; i += 256) { cnt[i] = 0; rnk[i] = 0; }
    __syncthreads();
    int beg = boff[b], end = boff[b + 1];
    for (int i = beg + t; i < end; i += 256) {
        atomicAdd(&cnt[temp[i] >> SRCB], 1);
    }
    __syncthreads();
    int v = (t < DPB) ? cnt[t] : 0;
    if (t < DPB) scn[t] = v;
    __syncthreads();
    for (int off = 1; off < DPB; off <<= 1) {
        int tv = (t >= off && t < DPB) ? scn[t - off] : 0;
        __syncthreads();
        if (t < DPB) scn[t] += tv;
        __syncthreads();
    }
    if (t < DPB) {
        int ob = beg + scn[t] - v;
        obase[t] = ob;
        if (dbase + t < nd) offsets[dbase + t] = ob;
    }
    __syncthreads();
    for (int i = beg + t; i < end; i += 256) {
        uint val = temp[i];
        int dlow = (int)(val >> SRCB);
        int s = (int)(val & ((1u << SRCB) - 1));
        int r = atomicAdd(&rnk[dlow], 1);
        edges[obase[dlow] + r] = s;
    }
}

// --- Wave-per-dst bf16 gather-mean, deep ILP, no LDS / no barriers ----------
// f128: 64 lanes x 4 B (uint = 2 bf16) = one 256 B row; lane owns its 2 feats.

__global__ __launch_bounds__(256) void gather_mean_f128(
    const ushort* __restrict__ xb, const int* __restrict__ edges,
    const int* __restrict__ offsets, ushort* __restrict__ outb) {
    int d = (blockIdx.x << 2) | (threadIdx.x >> 6);   // wave-per-dst, 4 waves/block
    int lane = threadIdx.x & 63;
    int beg = offsets[d], end = offsets[d + 1];
    float sx = 0.f, sy = 0.f;
    int i = beg;
    for (; i + 7 < end; i += 8) {
        int e0 = edges[i + 0], e1 = edges[i + 1], e2 = edges[i + 2], e3 = edges[i + 3];
        int e4 = edges[i + 4], e5 = edges[i + 5], e6 = edges[i + 6], e7 = edges[i + 7];
        uint v0 = ((const uint*)(xb + (size_t)e0 * IN_F))[lane];
        uint v1 = ((const uint*)(xb + (size_t)e1 * IN_F))[lane];
        uint v2 = ((const uint*)(xb + (size_t)e2 * IN_F))[lane];
        uint v3 = ((const uint*)(xb + (size_t)e3 * IN_F))[lane];
        uint v4 = ((const uint*)(xb + (size_t)e4 * IN_F))[lane];
        uint v5 = ((const uint*)(xb + (size_t)e5 * IN_F))[lane];
        uint v6 = ((const uint*)(xb + (size_t)e6 * IN_F))[lane];
        uint v7 = ((const uint*)(xb + (size_t)e7 * IN_F))[lane];
        sx += bf2f((ushort)(v0 & 0xffff)); sy += bf2f((ushort)(v0 >> 16));
        sx += bf2f((ushort)(v1 & 0xffff)); sy += bf2f((ushort)(v1 >> 16));
        sx += bf2f((ushort)(v2 & 0xffff)); sy += bf2f((ushort)(v2 >> 16));
        sx += bf2f((ushort)(v3 & 0xffff)); sy += bf2f((ushort)(v3 >> 16));
        sx += bf2f((ushort)(v4 & 0xffff)); sy += bf2f((ushort)(v4 >> 16));
        sx += bf2f((ushort)(v5 & 0xffff)); sy += bf2f((ushort)(v5 >> 16));
        sx += bf2f((ushort)(v6 & 0xffff)); sy += bf2f((ushort)(v6 >> 16));
        sx += bf2f((ushort)(v7 & 0xffff)); sy += bf2f((ushort)(v7 >> 16));
    }
    for (; i < end; ++i) {
        uint v = ((const uint*)(xb + (size_t)edges[i] * IN_F))[lane];
        sx += bf2f((ushort)(v & 0xffff));
        sy += bf2f((ushort)(v >> 16));
    }
    float inv = 1.0f / fmaxf((float)(end - beg), 1.0f);
    ((uint*)(outb + (size_t)d * IN_F))[lane] =
        (uint)f2bf(sx * inv) | ((uint)f2bf(sy * inv) << 16);
}

// f256: 64 lanes x 8 B (uint2 = 4 bf16) = one 512 B row; lane owns 4 feats.
__global__ __launch_bounds__(256) void gather_mean_f256(
    const ushort* __restrict__ hb, const int* __restrict__ edges,
    const int* __restrict__ offsets, ushort* __restrict__ outb) {
    int d = (blockIdx.x << 2) | (threadIdx.x >> 6);
    int lane = threadIdx.x & 63;
    int beg = offsets[d], end = offsets[d + 1];
    float s0 = 0.f, s1 = 0.f, s2 = 0.f, s3 = 0.f;
    int i = beg;
    for (; i + 3 < end; i += 4) {
        int e0 = edges[i + 0], e1 = edges[i + 1], e2 = edges[i + 2], e3 = edges[i + 3];
        uint2 v0 = ((const uint2*)(hb + (size_t)e0 * H_F))[lane];
        uint2 v1 = ((const uint2*)(hb + (size_t)e1 * H_F))[lane];
        uint2 v2 = ((const uint2*)(hb + (size_t)e2 * H_F))[lane];
        uint2 v3 = ((const uint2*)(hb + (size_t)e3 * H_F))[lane];
        s0 += bf2f((ushort)(v0.x & 0xffff)); s1 += bf2f((ushort)(v0.x >> 16));
        s2 += bf2f((ushort)(v0.y & 0xffff)); s3 += bf2f((ushort)(v0.y >> 16));
        s0 += bf2f((ushort)(v1.x & 0xffff)); s1 += bf2f((ushort)(v1.x >> 16));
        s2 += bf2f((ushort)(v1.y & 0xffff)); s3 += bf2f((ushort)(v1.y >> 16));
        s0 += bf2f((ushort)(v2.x & 0xffff)); s1 += bf2f((ushort)(v2.x >> 16));
        s2 += bf2f((ushort)(v2.y & 0xffff)); s3 += bf2f((ushort)(v2.y >> 16));
        s0 += bf2f((ushort)(v3.x & 0xffff)); s1 += bf2f((ushort)(v3.x >> 16));
        s2 += bf2f((ushort)(v3.y & 0xffff)); s3 += bf2f((ushort)(v3.y >> 16));
    }
    for (; i < end; ++i) {
        uint2 v = ((const uint2*)(hb + (size_t)edges[i] * H_F))[lane];
        s0 += bf2f((ushort)(v.x & 0xffff)); s1 += bf2f((ushort)(v.x >> 16));
        s2 += bf2f((ushort)(v.y & 0xffff)); s3 += bf2f((ushort)(v.y >> 16));
    }
    float inv = 1.0f / fmaxf((float)(end - beg), 1.0f);
    uint2 o;
    o.x = (uint)f2bf(s0 * inv) | ((uint)f2bf(s1 * inv) << 16);
    o.y = (uint)f2bf(s2 * inv) | ((uint)f2bf(s3 * inv) << 16);
    ((uint2*)(outb + (size_t)d * H_F))[lane] = o;
}

// --- MFMA GEMM: C = (relu?)([Aself|Aneigh] @ WT^T + bias) -------------------
// Block tile 64x64, 4 waves (2x2), each wave 32x32 via 2x2 frags of 16x16x32.

template <int K, int KSELF, bool RELU, bool OUTF32>
__global__ __launch_bounds__(256) void sage_mfma_gemm(
    const ushort* __restrict__ Aself, const ushort* __restrict__ Aneigh,
    const ushort* __restrict__ WT, const float* __restrict__ bias,
    void* __restrict__ Cout, int ldc, int ncols) {
    constexpr int KN = K - KSELF;
    constexpr int LDL = K + 8;  // LDS row stride in elems (+16B pad: 2-way conflicts only)
    __shared__ __align__(16) ushort A_lds[64 * LDL];
    __shared__ __align__(16) ushort B_lds[64 * LDL];
    int t = threadIdx.x;
    int bn = blockIdx.x * 64, bm = blockIdx.y * 64;
    constexpr int CPR = K / 8;            // 16B chunks per row
    constexpr int ITER = 64 * CPR / 256;  // staging iterations
#pragma unroll
    for (int c = 0; c < ITER; ++c) {
        int id = c * 256 + t;
        int row = id / CPR;
        int kc = (id % CPR) * 8;
        const ushort* sa = (kc < KSELF)
                               ? Aself + (size_t)(bm + row) * KSELF + kc
                               : Aneigh + (size_t)(bm + row) * KN + (kc - KSELF);
        float4 av = *(const float4*)sa;
        float4 bv = *(const float4*)(WT + (size_t)(bn + row) * K + kc);
        *(float4*)&A_lds[row * LDL + kc] = av;
        *(float4*)&B_lds[row * LDL + kc] = bv;
    }
    __syncthreads();
    int lane = t & 63, w = t >> 6;
    int wr = w >> 1, wc = w & 1;
    int ln = lane & 15, kh = lane >> 4;
    const ushort* Ab = &A_lds[(wr * 32 + ln) * LDL + kh * 8];
    const ushort* Bb = &B_lds[(wc * 32 + ln) * LDL + kh * 8];
    f32x4 acc00 = {0.f, 0.f, 0.f, 0.f};
    f32x4 acc01 = {0.f, 0.f, 0.f, 0.f};
    f32x4 acc10 = {0.f, 0.f, 0.f, 0.f};
    f32x4 acc11 = {0.f, 0.f, 0.f, 0.f};
#pragma unroll
    for (int kt = 0; kt < K / 32; ++kt) {
        bf16x8 a0 = *(const bf16x8*)(Ab + kt * 32);
        bf16x8 a1 = *(const bf16x8*)(Ab + 16 * LDL + kt * 32);
        bf16x8 b0 = *(const bf16x8*)(Bb + kt * 32);
        bf16x8 b1 = *(const bf16x8*)(Bb + 16 * LDL + kt * 32);
        acc00 = __builtin_amdgcn_mfma_f32_16x16x32_bf16(a0, b0, acc00, 0, 0, 0);
        acc01 = __builtin_amdgcn_mfma_f32_16x16x32_bf16(a0, b1, acc01, 0, 0, 0);
        acc10 = __builtin_amdgcn_mfma_f32_16x16x32_bf16(a1, b0, acc10, 0, 0, 0);
        acc11 = __builtin_amdgcn_mfma_f32_16x16x32_bf16(a1, b1, acc11, 0, 0, 0);
    }
    // Epilogue. C/D layout: col = lane&15, row = (lane>>4)*4 + reg.
    f32x4 accs[2][2] = {{acc00, acc01}, {acc10, acc11}};
#pragma unroll
    for (int m = 0; m < 2; ++m) {
#pragma unroll
        for (int n = 0; n < 2; ++n) {
            int col = bn + wc * 32 + n * 16 + ln;
            float bv = bias[col];
#pragma unroll
            for (int r = 0; r < 4; ++r) {
                int row = bm + wr * 32 + m * 16 + kh * 4 + r;
                float v = accs[m][n][r] + bv;
                if (RELU) v = fmaxf(v, 0.f);
                if (OUTF32) {
                    if (col < ncols) ((float*)Cout)[(size_t)row * ncols + col] = v;
                } else {
                    ((ushort*)Cout)[(size_t)row * ldc + col] = f2bf(v);
                }
            }
        }
    }
}

// ---------------------------------------------------------------------------

static inline char* carve(char*& p, size_t bytes) {
    char* r = p;
    p += (bytes + 255) & ~(size_t)255;
    return r;
}

extern "C" void kernel_launch(void* const* d_in, const int* in_sizes, int n_in,
                              void* d_out, int out_size, void* d_ws, size_t ws_size,
                              hipStream_t stream) {
    const float* x        = (const float*)d_in[0];
    const int*   src1     = (const int*)d_in[1];
    const int*   dst1     = (const int*)d_in[2];
    const int*   src2     = (const int*)d_in[3];
    const int*   dst2     = (const int*)d_in[4];
    const float* W_self1  = (const float*)d_in[7];
    const float* W_neigh1 = (const float*)d_in[8];
    const float* b1       = (const float*)d_in[9];
    const float* W_self2  = (const float*)d_in[10];
    const float* W_neigh2 = (const float*)d_in[11];
    const float* b2       = (const float*)d_in[12];
    float* out = (float*)d_out;

    const int E1 = in_sizes[1];
    const int E2 = in_sizes[3];

    // Coarse-bucket parameters
    constexpr int SHIFT1 = 7, NB1 = (N2_DST + 127) >> 7, SRCB1 = 18;  // 313 buckets
    constexpr int SHIFT2 = 6, NB2 = (N3_DST + 63) >> 6, SRCB2 = 16;   // 125 buckets

    char* p = (char*)d_ws;
    ushort* xb       = (ushort*)carve(p, (size_t)N1_SRC * IN_F * 2);   // 51.2 MB
    ushort* hb       = (ushort*)carve(p, (size_t)N2_DST * H_F * 2);    // 20.5 MB
    ushort* hneighb  = (ushort*)carve(p, (size_t)N2_DST * IN_F * 2);   // 10.2 MB
    ushort* hneigh2b = (ushort*)carve(p, (size_t)N3_DST * H_F * 2);    //  4.1 MB
    int*    edges    = (int*)carve(p, (size_t)E1 * 4);                 //  5.1 MB
    int*    offsets  = (int*)carve(p, (size_t)(N2_DST + 1) * 4);
    int*    bcnt     = (int*)carve(p, (size_t)(NB1 + 1) * 4);
    int*    boff     = (int*)carve(p, (size_t)(NB1 + 1) * 4);
    int*    gcursor  = (int*)carve(p, (size_t)NB1 * 4);
    ushort* WT1      = (ushort*)carve(p, (size_t)H_F * (IN_F * 2) * 2);  // 256x256 bf16
    ushort* WT2      = (ushort*)carve(p, (size_t)64 * (H_F * 2) * 2);    // 64x512 bf16
    float*  bias2p   = (float*)carve(p, 64 * 4);
    // temp (binned packed edges) aliases hneighb: liveness is disjoint
    // (temp: pass1->pass2; hneighb: gather->GEMM, which follow pass2).
    uint* temp = (uint*)hneighb;

    // --- one-time-per-call prep (cheap) ---
    {
        int n4 = N1_SRC * IN_F / 4;
        cast_f32_to_bf16<<<(n4 + 255) / 256, 256, 0, stream>>>(x, xb, n4);
        build_wt<<<H_F, 256, 0, stream>>>(W_self1, W_neigh1, WT1, H_F, IN_F, IN_F);
        build_wt<<<64, 256, 0, stream>>>(W_self2, W_neigh2, WT2, C_F, H_F, H_F);
        pad_bias<<<1, 64, 0, stream>>>(b2, bias2p, C_F, 64);
    }

    // ---------------- Layer 1 ----------------
    {
        hipMemsetAsync(bcnt, 0, (size_t)(NB1 + 1) * 4, stream);
        bucket_hist<NB1, SHIFT1, 16><<<(E1 + 4095) / 4096, 256, 0, stream>>>(dst1, bcnt, E1);
        bucket_scan<<<1, 512, 0, stream>>>(bcnt, boff, NB1, E1, offsets, N2_DST);
        hipMemcpyAsync(gcursor, boff, (size_t)NB1 * 4, hipMemcpyDeviceToDevice, stream);
        bin_pass1<NB1, SHIFT1, SRCB1, 4096><<<(E1 + 4095) / 4096, 256, 0, stream>>>(
            src1, dst1, gcursor, temp, E1);
        bin_pass2<SHIFT1, SRCB1><<<NB1, 256, 0, stream>>>(temp, boff, offsets, edges, N2_DST);
        gather_mean_f128<<<N2_DST / 4, 256, 0, stream>>>(xb, edges, offsets, hneighb);
        dim3 grid(H_F / 64, N2_DST / 64);  // 4 x 625
        sage_mfma_gemm<256, 128, true, false><<<grid, 256, 0, stream>>>(
            xb, hneighb, WT1, b1, hb, H_F, H_F);
    }

    // ---------------- Layer 2 ----------------
    {
        hipMemsetAsync(bcnt, 0, (size_t)(NB2 + 1) * 4, stream);
        bucket_hist<NB2, SHIFT2, 16><<<(E2 + 4095) / 4096, 256, 0, stream>>>(dst2, bcnt, E2);
        bucket_scan<<<1, 512, 0, stream>>>(bcnt, boff, NB2, E2, offsets, N3_DST);
        hipMemcpyAsync(gcursor, boff, (size_t)NB2 * 4, hipMemcpyDeviceToDevice, stream);
        bin_pass1<NB2, SHIFT2, SRCB2, 2048><<<(E2 + 2047) / 2048, 256, 0, stream>>>(
            src2, dst2, gcursor, temp, E2);
        bin_pass2<SHIFT2, SRCB2><<<NB2, 256, 0, stream>>>(temp, boff, offsets, edges, N3_DST);
        gather_mean_f256<<<N3_DST / 4, 256, 0, stream>>>(hb, edges, offsets, hneigh2b);
        dim3 grid(1, N3_DST / 64);  // 1 x 125
        sage_mfma_gemm<512, 256, false, true><<<grid, 256, 0, stream>>>(
            hb, hneigh2b, WT2, bias2p, out, C_F, C_F);
    }
}

// Round 8
// 170.440 us; speedup vs baseline: 20.4693x; 1.2395x over previous
//
#include <hip/hip_runtime.h>
#include <hip/hip_bf16.h>
#include <cstddef>

// ---------------------------------------------------------------------------
// SAGE 2-layer, bf16/MFMA edition. Compact launch graph (9 launches):
//   memset(bcnt) -> prep (cast x + coarse bucket hists L1+L2 + WT builds +
//   bias pad) -> bucket_scan2 (both layers, writes boff+gcursor+offsets[nd])
//   -> bin_pass1m (both layers; bucket runs w/ per-block reservation)
//   -> bin_pass2m (both layers; computes per-dst offsets in-block, writes
//   offsets[] and block-contiguous edges) -> gather1 -> GEMM1(128x128,BK=64)
//   -> gather2 -> GEMM2(64x64, K-resident).
// Fused dual GEMM per layer: C = [A_self | A_neigh] @ [W_self ; W_neigh] + b.
// Sizes fixed: N1=200000, N2=40000, N3=8000, E1=1280000, E2=256000,
// IN=128, H=256, C=47.  M1 padded 40000->40064 for the 128-row tile.
// ---------------------------------------------------------------------------

#define N1_SRC 200000
#define N2_DST 40000
#define N2_PAD 40064
#define N3_DST 8000
#define IN_F 128
#define H_F 256
#define C_F 47

// Bucketing: uniform SHIFT=7 (128 dst/bucket), SRCB=18 (src < 2^18) both layers.
#define BSHIFT 7
#define SRCB 18
#define NB1 313   // ceil(40000/128)
#define NB2 63    // ceil(8000/128)
#define CAST_BLOCKS 6250  // 6250*256 threads*4 float4 = 25.6M floats = 200000*128

typedef short bf16x8 __attribute__((ext_vector_type(8)));
typedef float f32x4 __attribute__((ext_vector_type(4)));

__device__ __forceinline__ float bf2f(ushort u) {
    union { uint i; float f; } v; v.i = ((uint)u) << 16; return v.f;
}
__device__ __forceinline__ ushort f2bf(float f) {
    union { float f; uint i; } v; v.f = f;
    uint r = v.i + 0x7FFF + ((v.i >> 16) & 1);
    return (ushort)(r >> 16);
}

// --- prep: cast x -> xb, bucket hists (both layers), WT builds, bias pad ----

__global__ __launch_bounds__(256) void prep_kernel(
    const float* __restrict__ x, ushort* __restrict__ xb,
    const int* __restrict__ dst1, int* __restrict__ bcnt1, int E1,
    const int* __restrict__ dst2, int* __restrict__ bcnt2, int E2,
    const float* __restrict__ Wself1, const float* __restrict__ Wneigh1,
    ushort* __restrict__ WT1,
    const float* __restrict__ Wself2, const float* __restrict__ Wneigh2,
    ushort* __restrict__ WT2,
    const float* __restrict__ b2, float* __restrict__ bias2p) {
    __shared__ int cnt[NB1];
    int bx = blockIdx.x, t = threadIdx.x;
    if (bx < CAST_BLOCKS) {
        const float4* in4 = (const float4*)x;
        ushort4* out4 = (ushort4*)xb;
        int base = bx * 1024 + t;
#pragma unroll
        for (int j = 0; j < 4; ++j) {
            float4 v = in4[base + j * 256];
            ushort4 o;
            o.x = f2bf(v.x); o.y = f2bf(v.y); o.z = f2bf(v.z); o.w = f2bf(v.w);
            out4[base + j * 256] = o;
        }
        return;
    }
    bx -= CAST_BLOCKS;
    if (bx < NB1 + NB2) {  // hist blocks: 4096 edges each
        const int* dst = (bx < NB1) ? dst1 : dst2;
        int* bcnt = (bx < NB1) ? bcnt1 : bcnt2;
        int E = (bx < NB1) ? E1 : E2;
        int hb = (bx < NB1) ? bx : bx - NB1;
        for (int i = t; i < NB1; i += 256) cnt[i] = 0;
        __syncthreads();
        int base = hb * 4096 + t;
#pragma unroll
        for (int i = 0; i < 16; ++i) {
            int e = base + i * 256;
            if (e < E) atomicAdd(&cnt[dst[e] >> BSHIFT], 1);
        }
        __syncthreads();
        for (int i = t; i < NB1; i += 256) {
            int c = cnt[i];
            if (c) atomicAdd(&bcnt[i], c);
        }
        return;
    }
    bx -= NB1 + NB2;
    if (bx < H_F) {  // WT1[n][k], n=bx, K=256 (self 128 | neigh 128)
        int n = bx;
        for (int k = t; k < 2 * IN_F; k += 256) {
            float v = (k < IN_F) ? Wself1[(size_t)k * H_F + n]
                                 : Wneigh1[(size_t)(k - IN_F) * H_F + n];
            WT1[(size_t)n * (2 * IN_F) + k] = f2bf(v);
        }
        return;
    }
    bx -= H_F;
    if (bx < 64) {  // WT2[n][k], n=bx (pad n>=47 with 0), K=512
        int n = bx;
        for (int k = t; k < 2 * H_F; k += 256) {
            float v = 0.f;
            if (n < C_F) v = (k < H_F) ? Wself2[(size_t)k * C_F + n]
                                       : Wneigh2[(size_t)(k - H_F) * C_F + n];
            WT2[(size_t)n * (2 * H_F) + k] = f2bf(v);
        }
        return;
    }
    bx -= 64;
    if (bx == 0 && t < 64) bias2p[t] = (t < C_F) ? b2[t] : 0.f;
}

// --- bucket scan: 2 blocks (layer 0/1); writes boff, gcursor, offsets[nd] ---

__global__ void bucket_scan2(
    const int* __restrict__ bcnt1, int* __restrict__ boff1, int* __restrict__ gcur1,
    int E1, int* __restrict__ off1,
    const int* __restrict__ bcnt2, int* __restrict__ boff2, int* __restrict__ gcur2,
    int E2, int* __restrict__ off2) {
    __shared__ int smem[512];
    int t = threadIdx.x;
    int L = blockIdx.x;
    const int nb = L ? NB2 : NB1;
    const int* bcnt = L ? bcnt2 : bcnt1;
    int* boff = L ? boff2 : boff1;
    int* gcur = L ? gcur2 : gcur1;
    int E = L ? E2 : E1;
    int* offs = L ? off2 : off1;
    int nd = L ? N3_DST : N2_DST;
    int v = (t < nb) ? bcnt[t] : 0;
    smem[t] = v;
    __syncthreads();
    for (int off = 1; off < 512; off <<= 1) {
        int tv = (t >= off) ? smem[t - off] : 0;
        __syncthreads();
        smem[t] += tv;
        __syncthreads();
    }
    if (t < nb) { int e = smem[t] - v; boff[t] = e; gcur[t] = e; }
    if (t == 0) { boff[nb] = E; offs[nd] = E; }
}

// --- bin pass1 (both layers; grid.y = layer): bucket runs, block-reserved ---

__global__ __launch_bounds__(256) void bin_pass1m(
    const int* __restrict__ src1, const int* __restrict__ dst1,
    int* __restrict__ gcur1, uint* __restrict__ temp1, int E1,
    const int* __restrict__ src2, const int* __restrict__ dst2,
    int* __restrict__ gcur2, uint* __restrict__ temp2, int E2) {
    __shared__ int cnt[NB1];
    __shared__ int rnk[NB1];
    __shared__ int gbase[NB1];
    int L = blockIdx.y;
    const int* src = L ? src2 : src1;
    const int* dst = L ? dst2 : dst1;
    int* gcur = L ? gcur2 : gcur1;
    uint* temp = L ? temp2 : temp1;
    int E = L ? E2 : E1;
    int t = threadIdx.x;
    int e0 = blockIdx.x * 4096;
    if (e0 >= E) return;
    for (int i = t; i < NB1; i += 256) { cnt[i] = 0; rnk[i] = 0; }
    __syncthreads();
#pragma unroll
    for (int i = 0; i < 16; ++i) {
        int e = e0 + i * 256 + t;
        if (e < E) atomicAdd(&cnt[dst[e] >> BSHIFT], 1);
    }
    __syncthreads();
    for (int b = t; b < NB1; b += 256) {
        int c = cnt[b];
        gbase[b] = c ? atomicAdd(&gcur[b], c) : 0;
    }
    __syncthreads();
#pragma unroll
    for (int i = 0; i < 16; ++i) {
        int e = e0 + i * 256 + t;
        if (e < E) {
            int d = dst[e];
            int b = d >> BSHIFT;
            int r = atomicAdd(&rnk[b], 1);
            uint val = ((uint)(d & 127) << SRCB) | (uint)src[e];
            temp[gbase[b] + r] = val;
        }
    }
}

// --- bin pass2 (both layers; grid = NB1+NB2): per-dst offsets + placement ---

__global__ __launch_bounds__(256) void bin_pass2m(
    const uint* __restrict__ temp1, const int* __restrict__ boff1,
    int* __restrict__ off1, int* __restrict__ edges1,
    const uint* __restrict__ temp2, const int* __restrict__ boff2,
    int* __restrict__ off2, int* __restrict__ edges2) {
    constexpr int DPB = 128;
    __shared__ int cnt[DPB];
    __shared__ int scn[DPB];
    __shared__ int obase[DPB];
    __shared__ int rnk[DPB];
    int b = blockIdx.x, t = threadIdx.x;
    int L = (b >= NB1);
    int lb = L ? b - NB1 : b;
    const uint* temp = L ? temp2 : temp1;
    const int* boff = L ? boff2 : boff1;
    int* offsets = L ? off2 : off1;
    int* edges = L ? edges2 : edges1;
    int nd = L ? N3_DST : N2_DST;
    int dbase = lb << BSHIFT;
    if (t < DPB) { cnt[t] = 0; rnk[t] = 0; }
    __syncthreads();
    int beg = boff[lb], end = boff[lb + 1];
    for (int i = beg + t; i < end; i += 256) {
        atomicAdd(&cnt[temp[i] >> SRCB], 1);
    }
    __syncthreads();
    int v = (t < DPB) ? cnt[t] : 0;
    if (t < DPB) scn[t] = v;
    __syncthreads();
    for (int off = 1; off < DPB; off <<= 1) {
        int tv = (t >= off && t < DPB) ? scn[t - off] : 0;
        __syncthreads();
        if (t < DPB) scn[t] += tv;
        __syncthreads();
    }
    if (t < DPB) {
        int ob = beg + scn[t] - v;
        obase[t] = ob;
        if (dbase + t < nd) offsets[dbase + t] = ob;
    }
    __syncthreads();
    for (int i = beg + t; i < end; i += 256) {
        uint val = temp[i];
        int dlow = (int)(val >> SRCB);
        int s = (int)(val & ((1u << SRCB) - 1));
        int r = atomicAdd(&rnk[dlow], 1);
        edges[obase[dlow] + r] = s;
    }
}

// --- Wave-per-dst bf16 gather-mean, deep ILP, no LDS / no barriers ----------

__global__ __launch_bounds__(256) void gather_mean_f128(
    const ushort* __restrict__ xb, const int* __restrict__ edges,
    const int* __restrict__ offsets, ushort* __restrict__ outb) {
    int d = (blockIdx.x << 2) | (threadIdx.x >> 6);
    int lane = threadIdx.x & 63;
    int beg = offsets[d], end = offsets[d + 1];
    float sx = 0.f, sy = 0.f;
    int i = beg;
    for (; i + 7 < end; i += 8) {
        int e0 = edges[i + 0], e1 = edges[i + 1], e2 = edges[i + 2], e3 = edges[i + 3];
        int e4 = edges[i + 4], e5 = edges[i + 5], e6 = edges[i + 6], e7 = edges[i + 7];
        uint v0 = ((const uint*)(xb + (size_t)e0 * IN_F))[lane];
        uint v1 = ((const uint*)(xb + (size_t)e1 * IN_F))[lane];
        uint v2 = ((const uint*)(xb + (size_t)e2 * IN_F))[lane];
        uint v3 = ((const uint*)(xb + (size_t)e3 * IN_F))[lane];
        uint v4 = ((const uint*)(xb + (size_t)e4 * IN_F))[lane];
        uint v5 = ((const uint*)(xb + (size_t)e5 * IN_F))[lane];
        uint v6 = ((const uint*)(xb + (size_t)e6 * IN_F))[lane];
        uint v7 = ((const uint*)(xb + (size_t)e7 * IN_F))[lane];
        sx += bf2f((ushort)(v0 & 0xffff)); sy += bf2f((ushort)(v0 >> 16));
        sx += bf2f((ushort)(v1 & 0xffff)); sy += bf2f((ushort)(v1 >> 16));
        sx += bf2f((ushort)(v2 & 0xffff)); sy += bf2f((ushort)(v2 >> 16));
        sx += bf2f((ushort)(v3 & 0xffff)); sy += bf2f((ushort)(v3 >> 16));
        sx += bf2f((ushort)(v4 & 0xffff)); sy += bf2f((ushort)(v4 >> 16));
        sx += bf2f((ushort)(v5 & 0xffff)); sy += bf2f((ushort)(v5 >> 16));
        sx += bf2f((ushort)(v6 & 0xffff)); sy += bf2f((ushort)(v6 >> 16));
        sx += bf2f((ushort)(v7 & 0xffff)); sy += bf2f((ushort)(v7 >> 16));
    }
    for (; i < end; ++i) {
        uint v = ((const uint*)(xb + (size_t)edges[i] * IN_F))[lane];
        sx += bf2f((ushort)(v & 0xffff));
        sy += bf2f((ushort)(v >> 16));
    }
    float inv = 1.0f / fmaxf((float)(end - beg), 1.0f);
    ((uint*)(outb + (size_t)d * IN_F))[lane] =
        (uint)f2bf(sx * inv) | ((uint)f2bf(sy * inv) << 16);
}

__global__ __launch_bounds__(256) void gather_mean_f256(
    const ushort* __restrict__ hb, const int* __restrict__ edges,
    const int* __restrict__ offsets, ushort* __restrict__ outb) {
    int d = (blockIdx.x << 2) | (threadIdx.x >> 6);
    int lane = threadIdx.x & 63;
    int beg = offsets[d], end = offsets[d + 1];
    float s0 = 0.f, s1 = 0.f, s2 = 0.f, s3 = 0.f;
    int i = beg;
    for (; i + 3 < end; i += 4) {
        int e0 = edges[i + 0], e1 = edges[i + 1], e2 = edges[i + 2], e3 = edges[i + 3];
        uint2 v0 = ((const uint2*)(hb + (size_t)e0 * H_F))[lane];
        uint2 v1 = ((const uint2*)(hb + (size_t)e1 * H_F))[lane];
        uint2 v2 = ((const uint2*)(hb + (size_t)e2 * H_F))[lane];
        uint2 v3 = ((const uint2*)(hb + (size_t)e3 * H_F))[lane];
        s0 += bf2f((ushort)(v0.x & 0xffff)); s1 += bf2f((ushort)(v0.x >> 16));
        s2 += bf2f((ushort)(v0.y & 0xffff)); s3 += bf2f((ushort)(v0.y >> 16));
        s0 += bf2f((ushort)(v1.x & 0xffff)); s1 += bf2f((ushort)(v1.x >> 16));
        s2 += bf2f((ushort)(v1.y & 0xffff)); s3 += bf2f((ushort)(v1.y >> 16));
        s0 += bf2f((ushort)(v2.x & 0xffff)); s1 += bf2f((ushort)(v2.x >> 16));
        s2 += bf2f((ushort)(v2.y & 0xffff)); s3 += bf2f((ushort)(v2.y >> 16));
        s0 += bf2f((ushort)(v3.x & 0xffff)); s1 += bf2f((ushort)(v3.x >> 16));
        s2 += bf2f((ushort)(v3.y & 0xffff)); s3 += bf2f((ushort)(v3.y >> 16));
    }
    for (; i < end; ++i) {
        uint2 v = ((const uint2*)(hb + (size_t)edges[i] * H_F))[lane];
        s0 += bf2f((ushort)(v.x & 0xffff)); s1 += bf2f((ushort)(v.x >> 16));
        s2 += bf2f((ushort)(v.y & 0xffff)); s3 += bf2f((ushort)(v.y >> 16));
    }
    float inv = 1.0f / fmaxf((float)(end - beg), 1.0f);
    uint2 o;
    o.x = (uint)f2bf(s0 * inv) | ((uint)f2bf(s1 * inv) << 16);
    o.y = (uint)f2bf(s2 * inv) | ((uint)f2bf(s3 * inv) << 16);
    ((uint2*)(outb + (size_t)d * H_F))[lane] = o;
}

// --- GEMM1: 128x128 tile, BK=64, 4 waves (2x2), 4x4 frags/wave, bf16 out ----
// hb = relu([xb | hneigh] @ WT1^T + b1).  M=N2_PAD, N=256, K=256.

__global__ __launch_bounds__(256) void sage_mfma_gemm128(
    const ushort* __restrict__ Aself, const ushort* __restrict__ Aneigh,
    const ushort* __restrict__ WT, const float* __restrict__ bias,
    ushort* __restrict__ Cout) {
    constexpr int LDL = 72;  // 64 + 8 pad
    __shared__ __align__(16) ushort A_lds[128 * LDL];
    __shared__ __align__(16) ushort B_lds[128 * LDL];
    int t = threadIdx.x;
    int bn = blockIdx.x * 128, bm = blockIdx.y * 128;
    int lane = t & 63, w = t >> 6;
    int wr = w >> 1, wc = w & 1;
    int ln = lane & 15, kh = lane >> 4;
    f32x4 acc[4][4] = {};
    for (int kt0 = 0; kt0 < 256; kt0 += 64) {
#pragma unroll
        for (int c = 0; c < 4; ++c) {
            int id = c * 256 + t;      // 0..1023: 128 rows x 8 chunks
            int row = id >> 3;
            int kc = (id & 7) * 8;
            int k = kt0 + kc;
            const ushort* sa = (k < IN_F)
                                   ? Aself + (size_t)(bm + row) * IN_F + k
                                   : Aneigh + (size_t)(bm + row) * IN_F + (k - IN_F);
            *(float4*)&A_lds[row * LDL + kc] = *(const float4*)sa;
            *(float4*)&B_lds[row * LDL + kc] =
                *(const float4*)(WT + (size_t)(bn + row) * 256 + k);
        }
        __syncthreads();
#pragma unroll
        for (int kt = 0; kt < 2; ++kt) {
            bf16x8 aF[4], bF[4];
#pragma unroll
            for (int m = 0; m < 4; ++m)
                aF[m] = *(const bf16x8*)&A_lds[(wr * 64 + m * 16 + ln) * LDL + kt * 32 + kh * 8];
#pragma unroll
            for (int n = 0; n < 4; ++n)
                bF[n] = *(const bf16x8*)&B_lds[(wc * 64 + n * 16 + ln) * LDL + kt * 32 + kh * 8];
#pragma unroll
            for (int m = 0; m < 4; ++m)
#pragma unroll
                for (int n = 0; n < 4; ++n)
                    acc[m][n] = __builtin_amdgcn_mfma_f32_16x16x32_bf16(
                        aF[m], bF[n], acc[m][n], 0, 0, 0);
        }
        __syncthreads();
    }
    // C/D layout: col = lane&15, row = (lane>>4)*4 + reg.
#pragma unroll
    for (int m = 0; m < 4; ++m) {
#pragma unroll
        for (int n = 0; n < 4; ++n) {
            int col = bn + wc * 64 + n * 16 + ln;
            float bv = bias[col];
#pragma unroll
            for (int r = 0; r < 4; ++r) {
                int row = bm + wr * 64 + m * 16 + kh * 4 + r;
                float v = fmaxf(acc[m][n][r] + bv, 0.f);
                Cout[(size_t)row * H_F + col] = f2bf(v);
            }
        }
    }
}

// --- GEMM2: 64x64 tile, whole K=512 LDS-resident, f32 out with col guard ----

template <int K, int KSELF, bool RELU, bool OUTF32>
__global__ __launch_bounds__(256) void sage_mfma_gemm(
    const ushort* __restrict__ Aself, const ushort* __restrict__ Aneigh,
    const ushort* __restrict__ WT, const float* __restrict__ bias,
    void* __restrict__ Cout, int ldc, int ncols) {
    constexpr int KN = K - KSELF;
    constexpr int LDL = K + 8;
    __shared__ __align__(16) ushort A_lds[64 * LDL];
    __shared__ __align__(16) ushort B_lds[64 * LDL];
    int t = threadIdx.x;
    int bn = blockIdx.x * 64, bm = blockIdx.y * 64;
    constexpr int CPR = K / 8;
    constexpr int ITER = 64 * CPR / 256;
#pragma unroll
    for (int c = 0; c < ITER; ++c) {
        int id = c * 256 + t;
        int row = id / CPR;
        int kc = (id % CPR) * 8;
        const ushort* sa = (kc < KSELF)
                               ? Aself + (size_t)(bm + row) * KSELF + kc
                               : Aneigh + (size_t)(bm + row) * KN + (kc - KSELF);
        float4 av = *(const float4*)sa;
        float4 bv = *(const float4*)(WT + (size_t)(bn + row) * K + kc);
        *(float4*)&A_lds[row * LDL + kc] = av;
        *(float4*)&B_lds[row * LDL + kc] = bv;
    }
    __syncthreads();
    int lane = t & 63, w = t >> 6;
    int wr = w >> 1, wc = w & 1;
    int ln = lane & 15, kh = lane >> 4;
    const ushort* Ab = &A_lds[(wr * 32 + ln) * LDL + kh * 8];
    const ushort* Bb = &B_lds[(wc * 32 + ln) * LDL + kh * 8];
    f32x4 acc00 = {0.f, 0.f, 0.f, 0.f};
    f32x4 acc01 = {0.f, 0.f, 0.f, 0.f};
    f32x4 acc10 = {0.f, 0.f, 0.f, 0.f};
    f32x4 acc11 = {0.f, 0.f, 0.f, 0.f};
#pragma unroll
    for (int kt = 0; kt < K / 32; ++kt) {
        bf16x8 a0 = *(const bf16x8*)(Ab + kt * 32);
        bf16x8 a1 = *(const bf16x8*)(Ab + 16 * LDL + kt * 32);
        bf16x8 b0 = *(const bf16x8*)(Bb + kt * 32);
        bf16x8 b1 = *(const bf16x8*)(Bb + 16 * LDL + kt * 32);
        acc00 = __builtin_amdgcn_mfma_f32_16x16x32_bf16(a0, b0, acc00, 0, 0, 0);
        acc01 = __builtin_amdgcn_mfma_f32_16x16x32_bf16(a0, b1, acc01, 0, 0, 0);
        acc10 = __builtin_amdgcn_mfma_f32_16x16x32_bf16(a1, b0, acc10, 0, 0, 0);
        acc11 = __builtin_amdgcn_mfma_f32_16x16x32_bf16(a1, b1, acc11, 0, 0, 0);
    }
    f32x4 accs[2][2] = {{acc00, acc01}, {acc10, acc11}};
#pragma unroll
    for (int m = 0; m < 2; ++m) {
#pragma unroll
        for (int n = 0; n < 2; ++n) {
            int col = bn + wc * 32 + n * 16 + ln;
            float bv = bias[col];
#pragma unroll
            for (int r = 0; r < 4; ++r) {
                int row = bm + wr * 32 + m * 16 + kh * 4 + r;
                float v = accs[m][n][r] + bv;
                if (RELU) v = fmaxf(v, 0.f);
                if (OUTF32) {
                    if (col < ncols) ((float*)Cout)[(size_t)row * ncols + col] = v;
                } else {
                    ((ushort*)Cout)[(size_t)row * ldc + col] = f2bf(v);
                }
            }
        }
    }
}

// ---------------------------------------------------------------------------

static inline char* carve(char*& p, size_t bytes) {
    char* r = p;
    p += (bytes + 255) & ~(size_t)255;
    return r;
}

extern "C" void kernel_launch(void* const* d_in, const int* in_sizes, int n_in,
                              void* d_out, int out_size, void* d_ws, size_t ws_size,
                              hipStream_t stream) {
    const float* x        = (const float*)d_in[0];
    const int*   src1     = (const int*)d_in[1];
    const int*   dst1     = (const int*)d_in[2];
    const int*   src2     = (const int*)d_in[3];
    const int*   dst2     = (const int*)d_in[4];
    const float* W_self1  = (const float*)d_in[7];
    const float* W_neigh1 = (const float*)d_in[8];
    const float* b1       = (const float*)d_in[9];
    const float* W_self2  = (const float*)d_in[10];
    const float* W_neigh2 = (const float*)d_in[11];
    const float* b2       = (const float*)d_in[12];
    float* out = (float*)d_out;

    const int E1 = in_sizes[1];
    const int E2 = in_sizes[3];

    char* p = (char*)d_ws;
    ushort* xb       = (ushort*)carve(p, (size_t)N1_SRC * IN_F * 2);   // 51.2 MB
    ushort* hb       = (ushort*)carve(p, (size_t)N2_PAD * H_F * 2);    // 20.5 MB
    ushort* hneighb  = (ushort*)carve(p, (size_t)N2_PAD * IN_F * 2);   // 10.3 MB
    ushort* hneigh2b = (ushort*)carve(p, (size_t)N3_DST * H_F * 2);    //  4.1 MB
    int*    edges1   = (int*)carve(p, (size_t)E1 * 4);                 //  5.1 MB
    int*    edges2   = (int*)carve(p, (size_t)E2 * 4);                 //  1.0 MB
    int*    off1     = (int*)carve(p, (size_t)(N2_DST + 1) * 4);
    int*    off2     = (int*)carve(p, (size_t)(N3_DST + 1) * 4);
    int*    bcnt     = (int*)carve(p, (size_t)(NB1 + NB2) * 4);        // contiguous -> 1 memset
    int*    bcnt1    = bcnt;
    int*    bcnt2    = bcnt + NB1;
    int*    boff1    = (int*)carve(p, (size_t)(NB1 + 1) * 4);
    int*    boff2    = (int*)carve(p, (size_t)(NB2 + 1) * 4);
    int*    gcur1    = (int*)carve(p, (size_t)NB1 * 4);
    int*    gcur2    = (int*)carve(p, (size_t)NB2 * 4);
    ushort* WT1      = (ushort*)carve(p, (size_t)H_F * (2 * IN_F) * 2);  // 256x256
    ushort* WT2      = (ushort*)carve(p, (size_t)64 * (2 * H_F) * 2);    // 64x512
    float*  bias2p   = (float*)carve(p, 64 * 4);
    // temp1/temp2 alias hneighb (liveness disjoint: temps die at pass2;
    // hneighb written by gather1 after pass2). 6.2 MB <= 10.3 MB.
    uint* temp1 = (uint*)hneighb;
    uint* temp2 = temp1 + E1;

    // 1) zero bucket counters (single small memset)
    hipMemsetAsync(bcnt, 0, (size_t)(NB1 + NB2) * 4, stream);

    // 2) prep: cast + hists (both layers) + WT builds + bias pad
    {
        int nblk = CAST_BLOCKS + (NB1 + NB2) + H_F + 64 + 1;
        prep_kernel<<<nblk, 256, 0, stream>>>(
            x, xb, dst1, bcnt1, E1, dst2, bcnt2, E2,
            W_self1, W_neigh1, WT1, W_self2, W_neigh2, WT2, b2, bias2p);
    }

    // 3) bucket scans (both layers)
    bucket_scan2<<<2, 512, 0, stream>>>(bcnt1, boff1, gcur1, E1, off1,
                                        bcnt2, boff2, gcur2, E2, off2);

    // 4) bin pass1 (both layers)
    {
        dim3 grid((E1 + 4095) / 4096, 2);
        bin_pass1m<<<grid, 256, 0, stream>>>(src1, dst1, gcur1, temp1, E1,
                                             src2, dst2, gcur2, temp2, E2);
    }

    // 5) bin pass2 (both layers)
    bin_pass2m<<<NB1 + NB2, 256, 0, stream>>>(temp1, boff1, off1, edges1,
                                              temp2, boff2, off2, edges2);

    // 6) layer-1 gather + GEMM
    gather_mean_f128<<<N2_DST / 4, 256, 0, stream>>>(xb, edges1, off1, hneighb);
    {
        dim3 grid(H_F / 128, N2_PAD / 128);  // 2 x 313
        sage_mfma_gemm128<<<grid, 256, 0, stream>>>(xb, hneighb, WT1, b1, hb);
    }

    // 7) layer-2 gather + GEMM
    gather_mean_f256<<<N3_DST / 4, 256, 0, stream>>>(hb, edges2, off2, hneigh2b);
    {
        dim3 grid(1, N3_DST / 64);  // 1 x 125
        sage_mfma_gemm<512, 256, false, true><<<grid, 256, 0, stream>>>(
            hb, hneigh2b, WT2, bias2p, out, C_F, C_F);
    }
}

// Round 9
// 165.934 us; speedup vs baseline: 21.0251x; 1.0272x over previous
//
#include <hip/hip_runtime.h>
#include <hip/hip_bf16.h>
#include <cstddef>

// ---------------------------------------------------------------------------
// SAGE 2-layer, bf16/MFMA edition. Compact launch graph (9 launches):
//   memset(bcnt) -> prep (cast x + coarse bucket hists L1+L2 + WT builds +
//   bias pad) -> bucket_scan2 -> bin_pass1m -> bin_pass2m ->
//   gather1 (uint4 wide) -> GEMM1(128x128,BK=64) -> gather2 (uint4 wide)
//   -> GEMM2(64x64, K-resident).
// Fused dual GEMM per layer: C = [A_self | A_neigh] @ [W_self ; W_neigh] + b.
// Sizes fixed: N1=200000, N2=40000, N3=8000, E1=1280000, E2=256000,
// IN=128, H=256, C=47.  M1 padded 40000->40064 for the 128-row tile.
// ---------------------------------------------------------------------------

#define N1_SRC 200000
#define N2_DST 40000
#define N2_PAD 40064
#define N3_DST 8000
#define IN_F 128
#define H_F 256
#define C_F 47

#define BSHIFT 7
#define SRCB 18
#define NB1 313   // ceil(40000/128)
#define NB2 63    // ceil(8000/128)
#define CAST_BLOCKS 6250

typedef short bf16x8 __attribute__((ext_vector_type(8)));
typedef float f32x4 __attribute__((ext_vector_type(4)));

__device__ __forceinline__ float bf2f(ushort u) {
    union { uint i; float f; } v; v.i = ((uint)u) << 16; return v.f;
}
__device__ __forceinline__ ushort f2bf(float f) {
    union { float f; uint i; } v; v.f = f;
    uint r = v.i + 0x7FFF + ((v.i >> 16) & 1);
    return (ushort)(r >> 16);
}
__device__ __forceinline__ uint pack2(float lo, float hi) {
    return (uint)f2bf(lo) | ((uint)f2bf(hi) << 16);
}
__device__ __forceinline__ void acc8(float* a, uint4 v) {
    a[0] += bf2f((ushort)(v.x & 0xffff)); a[1] += bf2f((ushort)(v.x >> 16));
    a[2] += bf2f((ushort)(v.y & 0xffff)); a[3] += bf2f((ushort)(v.y >> 16));
    a[4] += bf2f((ushort)(v.z & 0xffff)); a[5] += bf2f((ushort)(v.z >> 16));
    a[6] += bf2f((ushort)(v.w & 0xffff)); a[7] += bf2f((ushort)(v.w >> 16));
}

// --- prep: cast x -> xb, bucket hists (both layers), WT builds, bias pad ----

__global__ __launch_bounds__(256) void prep_kernel(
    const float* __restrict__ x, ushort* __restrict__ xb,
    const int* __restrict__ dst1, int* __restrict__ bcnt1, int E1,
    const int* __restrict__ dst2, int* __restrict__ bcnt2, int E2,
    const float* __restrict__ Wself1, const float* __restrict__ Wneigh1,
    ushort* __restrict__ WT1,
    const float* __restrict__ Wself2, const float* __restrict__ Wneigh2,
    ushort* __restrict__ WT2,
    const float* __restrict__ b2, float* __restrict__ bias2p) {
    __shared__ int cnt[NB1];
    int bx = blockIdx.x, t = threadIdx.x;
    if (bx < CAST_BLOCKS) {
        const float4* in4 = (const float4*)x;
        ushort4* out4 = (ushort4*)xb;
        int base = bx * 1024 + t;
#pragma unroll
        for (int j = 0; j < 4; ++j) {
            float4 v = in4[base + j * 256];
            ushort4 o;
            o.x = f2bf(v.x); o.y = f2bf(v.y); o.z = f2bf(v.z); o.w = f2bf(v.w);
            out4[base + j * 256] = o;
        }
        return;
    }
    bx -= CAST_BLOCKS;
    if (bx < NB1 + NB2) {
        const int* dst = (bx < NB1) ? dst1 : dst2;
        int* bcnt = (bx < NB1) ? bcnt1 : bcnt2;
        int E = (bx < NB1) ? E1 : E2;
        int hb = (bx < NB1) ? bx : bx - NB1;
        for (int i = t; i < NB1; i += 256) cnt[i] = 0;
        __syncthreads();
        int base = hb * 4096 + t;
#pragma unroll
        for (int i = 0; i < 16; ++i) {
            int e = base + i * 256;
            if (e < E) atomicAdd(&cnt[dst[e] >> BSHIFT], 1);
        }
        __syncthreads();
        for (int i = t; i < NB1; i += 256) {
            int c = cnt[i];
            if (c) atomicAdd(&bcnt[i], c);
        }
        return;
    }
    bx -= NB1 + NB2;
    if (bx < H_F) {
        int n = bx;
        for (int k = t; k < 2 * IN_F; k += 256) {
            float v = (k < IN_F) ? Wself1[(size_t)k * H_F + n]
                                 : Wneigh1[(size_t)(k - IN_F) * H_F + n];
            WT1[(size_t)n * (2 * IN_F) + k] = f2bf(v);
        }
        return;
    }
    bx -= H_F;
    if (bx < 64) {
        int n = bx;
        for (int k = t; k < 2 * H_F; k += 256) {
            float v = 0.f;
            if (n < C_F) v = (k < H_F) ? Wself2[(size_t)k * C_F + n]
                                       : Wneigh2[(size_t)(k - H_F) * C_F + n];
            WT2[(size_t)n * (2 * H_F) + k] = f2bf(v);
        }
        return;
    }
    bx -= 64;
    if (bx == 0 && t < 64) bias2p[t] = (t < C_F) ? b2[t] : 0.f;
}

// --- bucket scan: 2 blocks (layer 0/1); writes boff, gcursor, offsets[nd] ---

__global__ void bucket_scan2(
    const int* __restrict__ bcnt1, int* __restrict__ boff1, int* __restrict__ gcur1,
    int E1, int* __restrict__ off1,
    const int* __restrict__ bcnt2, int* __restrict__ boff2, int* __restrict__ gcur2,
    int E2, int* __restrict__ off2) {
    __shared__ int smem[512];
    int t = threadIdx.x;
    int L = blockIdx.x;
    const int nb = L ? NB2 : NB1;
    const int* bcnt = L ? bcnt2 : bcnt1;
    int* boff = L ? boff2 : boff1;
    int* gcur = L ? gcur2 : gcur1;
    int E = L ? E2 : E1;
    int* offs = L ? off2 : off1;
    int nd = L ? N3_DST : N2_DST;
    int v = (t < nb) ? bcnt[t] : 0;
    smem[t] = v;
    __syncthreads();
    for (int off = 1; off < 512; off <<= 1) {
        int tv = (t >= off) ? smem[t - off] : 0;
        __syncthreads();
        smem[t] += tv;
        __syncthreads();
    }
    if (t < nb) { int e = smem[t] - v; boff[t] = e; gcur[t] = e; }
    if (t == 0) { boff[nb] = E; offs[nd] = E; }
}

// --- bin pass1 (both layers; grid.y = layer): bucket runs, block-reserved ---

__global__ __launch_bounds__(256) void bin_pass1m(
    const int* __restrict__ src1, const int* __restrict__ dst1,
    int* __restrict__ gcur1, uint* __restrict__ temp1, int E1,
    const int* __restrict__ src2, const int* __restrict__ dst2,
    int* __restrict__ gcur2, uint* __restrict__ temp2, int E2) {
    __shared__ int cnt[NB1];
    __shared__ int rnk[NB1];
    __shared__ int gbase[NB1];
    int L = blockIdx.y;
    const int* src = L ? src2 : src1;
    const int* dst = L ? dst2 : dst1;
    int* gcur = L ? gcur2 : gcur1;
    uint* temp = L ? temp2 : temp1;
    int E = L ? E2 : E1;
    int t = threadIdx.x;
    int e0 = blockIdx.x * 4096;
    if (e0 >= E) return;
    for (int i = t; i < NB1; i += 256) { cnt[i] = 0; rnk[i] = 0; }
    __syncthreads();
#pragma unroll
    for (int i = 0; i < 16; ++i) {
        int e = e0 + i * 256 + t;
        if (e < E) atomicAdd(&cnt[dst[e] >> BSHIFT], 1);
    }
    __syncthreads();
    for (int b = t; b < NB1; b += 256) {
        int c = cnt[b];
        gbase[b] = c ? atomicAdd(&gcur[b], c) : 0;
    }
    __syncthreads();
#pragma unroll
    for (int i = 0; i < 16; ++i) {
        int e = e0 + i * 256 + t;
        if (e < E) {
            int d = dst[e];
            int b = d >> BSHIFT;
            int r = atomicAdd(&rnk[b], 1);
            uint val = ((uint)(d & 127) << SRCB) | (uint)src[e];
            temp[gbase[b] + r] = val;
        }
    }
}

// --- bin pass2 (both layers; grid = NB1+NB2): per-dst offsets + placement ---

__global__ __launch_bounds__(256) void bin_pass2m(
    const uint* __restrict__ temp1, const int* __restrict__ boff1,
    int* __restrict__ off1, int* __restrict__ edges1,
    const uint* __restrict__ temp2, const int* __restrict__ boff2,
    int* __restrict__ off2, int* __restrict__ edges2) {
    constexpr int DPB = 128;
    __shared__ int cnt[DPB];
    __shared__ int scn[DPB];
    __shared__ int obase[DPB];
    __shared__ int rnk[DPB];
    int b = blockIdx.x, t = threadIdx.x;
    int L = (b >= NB1);
    int lb = L ? b - NB1 : b;
    const uint* temp = L ? temp2 : temp1;
    const int* boff = L ? boff2 : boff1;
    int* offsets = L ? off2 : off1;
    int* edges = L ? edges2 : edges1;
    int nd = L ? N3_DST : N2_DST;
    int dbase = lb << BSHIFT;
    if (t < DPB) { cnt[t] = 0; rnk[t] = 0; }
    __syncthreads();
    int beg = boff[lb], end = boff[lb + 1];
    for (int i = beg + t; i < end; i += 256) {
        atomicAdd(&cnt[temp[i] >> SRCB], 1);
    }
    __syncthreads();
    int v = (t < DPB) ? cnt[t] : 0;
    if (t < DPB) scn[t] = v;
    __syncthreads();
    for (int off = 1; off < DPB; off <<= 1) {
        int tv = (t >= off && t < DPB) ? scn[t - off] : 0;
        __syncthreads();
        if (t < DPB) scn[t] += tv;
        __syncthreads();
    }
    if (t < DPB) {
        int ob = beg + scn[t] - v;
        obase[t] = ob;
        if (dbase + t < nd) offsets[dbase + t] = ob;
    }
    __syncthreads();
    for (int i = beg + t; i < end; i += 256) {
        uint val = temp[i];
        int dlow = (int)(val >> SRCB);
        int s = (int)(val & ((1u << SRCB) - 1));
        int r = atomicAdd(&rnk[dlow], 1);
        edges[obase[dlow] + r] = s;
    }
}

// --- Wave-per-dst wide gathers: uint4 (16 B) per lane -----------------------
// f128: 16 lanes cover one 256 B row -> 4 edges per load instruction.
// Per-lane 8-feat f32 accumulators; combine slots via shfl_xor(16/32).

__global__ __launch_bounds__(256) void gather_mean_f128(
    const ushort* __restrict__ xb, const int* __restrict__ edges,
    const int* __restrict__ offsets, ushort* __restrict__ outb) {
    int d = (blockIdx.x << 2) | (threadIdx.x >> 6);
    int lane = threadIdx.x & 63;
    int eslot = lane >> 4, lpos = lane & 15;
    int beg = offsets[d], end = offsets[d + 1];
    float a[8] = {};
    int i = beg;
    // 16 edges per iter: 4 slots x unroll 4 -> 4 KB in flight per wave
    for (; i + 16 <= end; i += 16) {
        int e0 = edges[i + eslot];
        int e1 = edges[i + 4 + eslot];
        int e2 = edges[i + 8 + eslot];
        int e3 = edges[i + 12 + eslot];
        uint4 v0 = ((const uint4*)(xb + (size_t)e0 * IN_F))[lpos];
        uint4 v1 = ((const uint4*)(xb + (size_t)e1 * IN_F))[lpos];
        uint4 v2 = ((const uint4*)(xb + (size_t)e2 * IN_F))[lpos];
        uint4 v3 = ((const uint4*)(xb + (size_t)e3 * IN_F))[lpos];
        acc8(a, v0); acc8(a, v1); acc8(a, v2); acc8(a, v3);
    }
    for (; i < end; i += 4) {
        if (i + eslot < end) {
            int e = edges[i + eslot];
            uint4 v = ((const uint4*)(xb + (size_t)e * IN_F))[lpos];
            acc8(a, v);
        }
    }
#pragma unroll
    for (int j = 0; j < 8; ++j) {
        a[j] += __shfl_xor(a[j], 16);
        a[j] += __shfl_xor(a[j], 32);
    }
    if (eslot == 0) {
        float inv = 1.0f / fmaxf((float)(end - beg), 1.0f);
        uint4 o;
        o.x = pack2(a[0] * inv, a[1] * inv);
        o.y = pack2(a[2] * inv, a[3] * inv);
        o.z = pack2(a[4] * inv, a[5] * inv);
        o.w = pack2(a[6] * inv, a[7] * inv);
        ((uint4*)(outb + (size_t)d * IN_F))[lpos] = o;
    }
}

// f256: 32 lanes cover one 512 B row -> 2 edges per load instruction.
__global__ __launch_bounds__(256) void gather_mean_f256(
    const ushort* __restrict__ hb, const int* __restrict__ edges,
    const int* __restrict__ offsets, ushort* __restrict__ outb) {
    int d = (blockIdx.x << 2) | (threadIdx.x >> 6);
    int lane = threadIdx.x & 63;
    int eslot = lane >> 5, lpos = lane & 31;
    int beg = offsets[d], end = offsets[d + 1];
    float a[8] = {};
    int i = beg;
    // 8 edges per iter: 2 slots x unroll 4 -> 4 KB in flight per wave
    for (; i + 8 <= end; i += 8) {
        int e0 = edges[i + eslot];
        int e1 = edges[i + 2 + eslot];
        int e2 = edges[i + 4 + eslot];
        int e3 = edges[i + 6 + eslot];
        uint4 v0 = ((const uint4*)(hb + (size_t)e0 * H_F))[lpos];
        uint4 v1 = ((const uint4*)(hb + (size_t)e1 * H_F))[lpos];
        uint4 v2 = ((const uint4*)(hb + (size_t)e2 * H_F))[lpos];
        uint4 v3 = ((const uint4*)(hb + (size_t)e3 * H_F))[lpos];
        acc8(a, v0); acc8(a, v1); acc8(a, v2); acc8(a, v3);
    }
    for (; i < end; i += 2) {
        if (i + eslot < end) {
            int e = edges[i + eslot];
            uint4 v = ((const uint4*)(hb + (size_t)e * H_F))[lpos];
            acc8(a, v);
        }
    }
#pragma unroll
    for (int j = 0; j < 8; ++j) {
        a[j] += __shfl_xor(a[j], 32);
    }
    if (eslot == 0) {
        float inv = 1.0f / fmaxf((float)(end - beg), 1.0f);
        uint4 o;
        o.x = pack2(a[0] * inv, a[1] * inv);
        o.y = pack2(a[2] * inv, a[3] * inv);
        o.z = pack2(a[4] * inv, a[5] * inv);
        o.w = pack2(a[6] * inv, a[7] * inv);
        ((uint4*)(outb + (size_t)d * H_F))[lpos] = o;
    }
}

// --- GEMM1: 128x128 tile, BK=64, 4 waves (2x2), 4x4 frags/wave, bf16 out ----

__global__ __launch_bounds__(256) void sage_mfma_gemm128(
    const ushort* __restrict__ Aself, const ushort* __restrict__ Aneigh,
    const ushort* __restrict__ WT, const float* __restrict__ bias,
    ushort* __restrict__ Cout) {
    constexpr int LDL = 72;
    __shared__ __align__(16) ushort A_lds[128 * LDL];
    __shared__ __align__(16) ushort B_lds[128 * LDL];
    int t = threadIdx.x;
    int bn = blockIdx.x * 128, bm = blockIdx.y * 128;
    int lane = t & 63, w = t >> 6;
    int wr = w >> 1, wc = w & 1;
    int ln = lane & 15, kh = lane >> 4;
    f32x4 acc[4][4] = {};
    for (int kt0 = 0; kt0 < 256; kt0 += 64) {
#pragma unroll
        for (int c = 0; c < 4; ++c) {
            int id = c * 256 + t;
            int row = id >> 3;
            int kc = (id & 7) * 8;
            int k = kt0 + kc;
            const ushort* sa = (k < IN_F)
                                   ? Aself + (size_t)(bm + row) * IN_F + k
                                   : Aneigh + (size_t)(bm + row) * IN_F + (k - IN_F);
            *(float4*)&A_lds[row * LDL + kc] = *(const float4*)sa;
            *(float4*)&B_lds[row * LDL + kc] =
                *(const float4*)(WT + (size_t)(bn + row) * 256 + k);
        }
        __syncthreads();
#pragma unroll
        for (int kt = 0; kt < 2; ++kt) {
            bf16x8 aF[4], bF[4];
#pragma unroll
            for (int m = 0; m < 4; ++m)
                aF[m] = *(const bf16x8*)&A_lds[(wr * 64 + m * 16 + ln) * LDL + kt * 32 + kh * 8];
#pragma unroll
            for (int n = 0; n < 4; ++n)
                bF[n] = *(const bf16x8*)&B_lds[(wc * 64 + n * 16 + ln) * LDL + kt * 32 + kh * 8];
#pragma unroll
            for (int m = 0; m < 4; ++m)
#pragma unroll
                for (int n = 0; n < 4; ++n)
                    acc[m][n] = __builtin_amdgcn_mfma_f32_16x16x32_bf16(
                        aF[m], bF[n], acc[m][n], 0, 0, 0);
        }
        __syncthreads();
    }
#pragma unroll
    for (int m = 0; m < 4; ++m) {
#pragma unroll
        for (int n = 0; n < 4; ++n) {
            int col = bn + wc * 64 + n * 16 + ln;
            float bv = bias[col];
#pragma unroll
            for (int r = 0; r < 4; ++r) {
                int row = bm + wr * 64 + m * 16 + kh * 4 + r;
                float v = fmaxf(acc[m][n][r] + bv, 0.f);
                Cout[(size_t)row * H_F + col] = f2bf(v);
            }
        }
    }
}

// --- GEMM2: 64x64 tile, whole K=512 LDS-resident, f32 out with col guard ----

template <int K, int KSELF, bool RELU, bool OUTF32>
__global__ __launch_bounds__(256) void sage_mfma_gemm(
    const ushort* __restrict__ Aself, const ushort* __restrict__ Aneigh,
    const ushort* __restrict__ WT, const float* __restrict__ bias,
    void* __restrict__ Cout, int ldc, int ncols) {
    constexpr int KN = K - KSELF;
    constexpr int LDL = K + 8;
    __shared__ __align__(16) ushort A_lds[64 * LDL];
    __shared__ __align__(16) ushort B_lds[64 * LDL];
    int t = threadIdx.x;
    int bn = blockIdx.x * 64, bm = blockIdx.y * 64;
    constexpr int CPR = K / 8;
    constexpr int ITER = 64 * CPR / 256;
#pragma unroll
    for (int c = 0; c < ITER; ++c) {
        int id = c * 256 + t;
        int row = id / CPR;
        int kc = (id % CPR) * 8;
        const ushort* sa = (kc < KSELF)
                               ? Aself + (size_t)(bm + row) * KSELF + kc
                               : Aneigh + (size_t)(bm + row) * KN + (kc - KSELF);
        float4 av = *(const float4*)sa;
        float4 bv = *(const float4*)(WT + (size_t)(bn + row) * K + kc);
        *(float4*)&A_lds[row * LDL + kc] = av;
        *(float4*)&B_lds[row * LDL + kc] = bv;
    }
    __syncthreads();
    int lane = t & 63, w = t >> 6;
    int wr = w >> 1, wc = w & 1;
    int ln = lane & 15, kh = lane >> 4;
    const ushort* Ab = &A_lds[(wr * 32 + ln) * LDL + kh * 8];
    const ushort* Bb = &B_lds[(wc * 32 + ln) * LDL + kh * 8];
    f32x4 acc00 = {0.f, 0.f, 0.f, 0.f};
    f32x4 acc01 = {0.f, 0.f, 0.f, 0.f};
    f32x4 acc10 = {0.f, 0.f, 0.f, 0.f};
    f32x4 acc11 = {0.f, 0.f, 0.f, 0.f};
#pragma unroll
    for (int kt = 0; kt < K / 32; ++kt) {
        bf16x8 a0 = *(const bf16x8*)(Ab + kt * 32);
        bf16x8 a1 = *(const bf16x8*)(Ab + 16 * LDL + kt * 32);
        bf16x8 b0 = *(const bf16x8*)(Bb + kt * 32);
        bf16x8 b1 = *(const bf16x8*)(Bb + 16 * LDL + kt * 32);
        acc00 = __builtin_amdgcn_mfma_f32_16x16x32_bf16(a0, b0, acc00, 0, 0, 0);
        acc01 = __builtin_amdgcn_mfma_f32_16x16x32_bf16(a0, b1, acc01, 0, 0, 0);
        acc10 = __builtin_amdgcn_mfma_f32_16x16x32_bf16(a1, b0, acc10, 0, 0, 0);
        acc11 = __builtin_amdgcn_mfma_f32_16x16x32_bf16(a1, b1, acc11, 0, 0, 0);
    }
    f32x4 accs[2][2] = {{acc00, acc01}, {acc10, acc11}};
#pragma unroll
    for (int m = 0; m < 2; ++m) {
#pragma unroll
        for (int n = 0; n < 2; ++n) {
            int col = bn + wc * 32 + n * 16 + ln;
            float bv = bias[col];
#pragma unroll
            for (int r = 0; r < 4; ++r) {
                int row = bm + wr * 32 + m * 16 + kh * 4 + r;
                float v = accs[m][n][r] + bv;
                if (RELU) v = fmaxf(v, 0.f);
                if (OUTF32) {
                    if (col < ncols) ((float*)Cout)[(size_t)row * ncols + col] = v;
                } else {
                    ((ushort*)Cout)[(size_t)row * ldc + col] = f2bf(v);
                }
            }
        }
    }
}

// ---------------------------------------------------------------------------

static inline char* carve(char*& p, size_t bytes) {
    char* r = p;
    p += (bytes + 255) & ~(size_t)255;
    return r;
}

extern "C" void kernel_launch(void* const* d_in, const int* in_sizes, int n_in,
                              void* d_out, int out_size, void* d_ws, size_t ws_size,
                              hipStream_t stream) {
    const float* x        = (const float*)d_in[0];
    const int*   src1     = (const int*)d_in[1];
    const int*   dst1     = (const int*)d_in[2];
    const int*   src2     = (const int*)d_in[3];
    const int*   dst2     = (const int*)d_in[4];
    const float* W_self1  = (const float*)d_in[7];
    const float* W_neigh1 = (const float*)d_in[8];
    const float* b1       = (const float*)d_in[9];
    const float* W_self2  = (const float*)d_in[10];
    const float* W_neigh2 = (const float*)d_in[11];
    const float* b2       = (const float*)d_in[12];
    float* out = (float*)d_out;

    const int E1 = in_sizes[1];
    const int E2 = in_sizes[3];

    char* p = (char*)d_ws;
    ushort* xb       = (ushort*)carve(p, (size_t)N1_SRC * IN_F * 2);
    ushort* hb       = (ushort*)carve(p, (size_t)N2_PAD * H_F * 2);
    ushort* hneighb  = (ushort*)carve(p, (size_t)N2_PAD * IN_F * 2);
    ushort* hneigh2b = (ushort*)carve(p, (size_t)N3_DST * H_F * 2);
    int*    edges1   = (int*)carve(p, (size_t)E1 * 4);
    int*    edges2   = (int*)carve(p, (size_t)E2 * 4);
    int*    off1     = (int*)carve(p, (size_t)(N2_DST + 1) * 4);
    int*    off2     = (int*)carve(p, (size_t)(N3_DST + 1) * 4);
    int*    bcnt     = (int*)carve(p, (size_t)(NB1 + NB2) * 4);
    int*    bcnt1    = bcnt;
    int*    bcnt2    = bcnt + NB1;
    int*    boff1    = (int*)carve(p, (size_t)(NB1 + 1) * 4);
    int*    boff2    = (int*)carve(p, (size_t)(NB2 + 1) * 4);
    int*    gcur1    = (int*)carve(p, (size_t)NB1 * 4);
    int*    gcur2    = (int*)carve(p, (size_t)NB2 * 4);
    ushort* WT1      = (ushort*)carve(p, (size_t)H_F * (2 * IN_F) * 2);
    ushort* WT2      = (ushort*)carve(p, (size_t)64 * (2 * H_F) * 2);
    float*  bias2p   = (float*)carve(p, 64 * 4);
    uint* temp1 = (uint*)hneighb;
    uint* temp2 = temp1 + E1;

    hipMemsetAsync(bcnt, 0, (size_t)(NB1 + NB2) * 4, stream);

    {
        int nblk = CAST_BLOCKS + (NB1 + NB2) + H_F + 64 + 1;
        prep_kernel<<<nblk, 256, 0, stream>>>(
            x, xb, dst1, bcnt1, E1, dst2, bcnt2, E2,
            W_self1, W_neigh1, WT1, W_self2, W_neigh2, WT2, b2, bias2p);
    }

    bucket_scan2<<<2, 512, 0, stream>>>(bcnt1, boff1, gcur1, E1, off1,
                                        bcnt2, boff2, gcur2, E2, off2);

    {
        dim3 grid((E1 + 4095) / 4096, 2);
        bin_pass1m<<<grid, 256, 0, stream>>>(src1, dst1, gcur1, temp1, E1,
                                             src2, dst2, gcur2, temp2, E2);
    }

    bin_pass2m<<<NB1 + NB2, 256, 0, stream>>>(temp1, boff1, off1, edges1,
                                              temp2, boff2, off2, edges2);

    gather_mean_f128<<<N2_DST / 4, 256, 0, stream>>>(xb, edges1, off1, hneighb);
    {
        dim3 grid(H_F / 128, N2_PAD / 128);
        sage_mfma_gemm128<<<grid, 256, 0, stream>>>(xb, hneighb, WT1, b1, hb);
    }

    gather_mean_f256<<<N3_DST / 4, 256, 0, stream>>>(hb, edges2, off2, hneigh2b);
    {
        dim3 grid(1, N3_DST / 64);
        sage_mfma_gemm<512, 256, false, true><<<grid, 256, 0, stream>>>(
            hb, hneigh2b, WT2, bias2p, out, C_F, C_F);
    }
}